// Round 2
// baseline (1860.358 us; speedup 1.0000x reference)
//
#include <hip/hip_runtime.h>

#define N_ROWS 65536
#define K_CODES 4096
#define D_DIM 256

#define TN 64
#define TK 128
#define DB 64
#define LDSS 68            // padded LDS stride (floats); keeps float4 alignment

// ---------------- ws layout ----------------
// [0]       float  rownorm[65536]   (256 KB)
// [262144]  float  cvec[4096]       (16 KB)
// [278528]  double partials[2048]   (16 KB)

// ---------------- norms: f64 sum of f32 squares, rounded once ----------------
// 64 rows per block; 4 threads per row; fully-coalesced 64B-per-quad loads.
__global__ __launch_bounds__(256) void norm_kernel(const float* __restrict__ src,
                                                   float* __restrict__ dst) {
    int row = blockIdx.x * 64 + (threadIdx.x >> 2);
    int q = threadIdx.x & 3;
    const float* p = src + (size_t)row * D_DIM;
    double acc = 0.0;
#pragma unroll 4
    for (int it = 0; it < 16; ++it) {
        float4 v = *(const float4*)&p[(q + 4 * it) * 4];
        float a = v.x * v.x;   // f32-rounded squares (matches np's z**2 then sum)
        float b = v.y * v.y;
        float c = v.z * v.z;
        float d = v.w * v.w;
        acc += (double)a; acc += (double)b; acc += (double)c; acc += (double)d;
    }
    acc += __shfl_xor(acc, 1);
    acc += __shfl_xor(acc, 2);
    if (q == 0) dst[row] = (float)acc;
}

// ---------------- phase A: f32 GEMM + quantized-f32 argmin ----------------
__global__ __launch_bounds__(256, 1) void phaseA_kernel(
        const float* __restrict__ z, const float* __restrict__ emb,
        const float* __restrict__ rownorm, const float* __restrict__ cvec,
        float* __restrict__ out_idx) {
    __shared__ float zs[TN * LDSS];   // 17408 B
    __shared__ float es[TK * LDSS];   // 34816 B

    const int tid = threadIdx.x;
    const int rt = tid >> 5;          // 0..7  -> rows rt*8 .. rt*8+7
    const int ct = tid & 31;          // 0..31 -> codes ct, ct+32, ct+64, ct+96
    const int rowbase = blockIdx.x * TN;

    float a_r[8];
#pragma unroll
    for (int r = 0; r < 8; ++r) a_r[r] = rownorm[rowbase + rt * 8 + r];

    float m1[8];
    int i1[8];
#pragma unroll
    for (int r = 0; r < 8; ++r) { m1[r] = 3.4e38f; i1[r] = 0; }

    for (int kb = 0; kb < K_CODES / TK; ++kb) {
        float acc[8][4] = {};
        for (int db = 0; db < D_DIM / DB; ++db) {
            // stage z tile: 64 rows x 64 floats = 1024 float4, 4 per thread
#pragma unroll
            for (int j = 0; j < 4; ++j) {
                int v = j * 256 + tid;
                int row = v >> 4, c4 = v & 15;
                float4 t = *(const float4*)&z[(size_t)(rowbase + row) * D_DIM + db * DB + c4 * 4];
                *(float4*)&zs[row * LDSS + c4 * 4] = t;
            }
            // stage e tile: 128 codes x 64 floats = 2048 float4, 8 per thread
#pragma unroll
            for (int j = 0; j < 8; ++j) {
                int v = j * 256 + tid;
                int code = v >> 4, c4 = v & 15;
                float4 t = *(const float4*)&emb[(size_t)(kb * TK + code) * D_DIM + db * DB + c4 * 4];
                *(float4*)&es[code * LDSS + c4 * 4] = t;
            }
            __syncthreads();
#pragma unroll 4
            for (int i4 = 0; i4 < DB / 4; ++i4) {
                float4 zf[8], ef[4];
#pragma unroll
                for (int r = 0; r < 8; ++r)
                    zf[r] = *(const float4*)&zs[(rt * 8 + r) * LDSS + i4 * 4];
#pragma unroll
                for (int c = 0; c < 4; ++c)
                    ef[c] = *(const float4*)&es[(ct + 32 * c) * LDSS + i4 * 4];
#pragma unroll
                for (int c = 0; c < 4; ++c)
#pragma unroll
                    for (int r = 0; r < 8; ++r) {
                        acc[r][c] = fmaf(zf[r].x, ef[c].x, acc[r][c]);
                        acc[r][c] = fmaf(zf[r].y, ef[c].y, acc[r][c]);
                        acc[r][c] = fmaf(zf[r].z, ef[c].z, acc[r][c]);
                        acc[r][c] = fmaf(zf[r].w, ef[c].w, acc[r][c]);
                    }
            }
            __syncthreads();
        }
        // epilogue: replicate np f32 rounding: d = fl(fl(a - fl(2*dot)) + c).
        // __f*_rn intrinsics block -ffp-contract=fast from fusing a-2*acc.
#pragma unroll
        for (int c = 0; c < 4; ++c) {
            int k = kb * TK + ct + 32 * c;
            float ck = cvec[k];
#pragma unroll
            for (int r = 0; r < 8; ++r) {
                float t1 = __fsub_rn(a_r[r], __fmul_rn(2.0f, acc[r][c]));
                float d  = __fadd_rn(t1, ck);
                if (d < m1[r]) { m1[r] = d; i1[r] = k; }   // strict < : first index wins
            }
        }
    }

    // merge argmin across the 32 ct-lanes (butterfly; first-index tie-break)
#pragma unroll
    for (int r = 0; r < 8; ++r) {
        float a1 = m1[r];
        int ai = i1[r];
        for (int m = 16; m >= 1; m >>= 1) {
            float b1 = __shfl_xor(a1, m);
            int   bi = __shfl_xor(ai, m);
            if (b1 < a1 || (b1 == a1 && bi < ai)) { a1 = b1; ai = bi; }
        }
        if (ct == 0) out_idx[rowbase + rt * 8 + r] = (float)ai;
    }
}

// ---------------- writeback z_q_st + loss partials ----------------
__global__ __launch_bounds__(256) void writeback_kernel(
        const float* __restrict__ z, const float* __restrict__ emb,
        const float* __restrict__ out_idx, float* __restrict__ out0,
        double* __restrict__ partials) {
    const int tid = threadIdx.x;
    const int base = blockIdx.x * 32;
    double acc = 0.0;
    for (int g = 0; g < 8; ++g) {
        int row = base + g * 4 + (tid >> 6);
        int d4 = tid & 63;
        int idx = (int)out_idx[row];
        float4 q4 = *(const float4*)&emb[(size_t)idx * D_DIM + d4 * 4];
        float4 z4 = *(const float4*)&z[(size_t)row * D_DIM + d4 * 4];
        // z_q_st = z + (z_q - z), f32 ops as in the reference
        float4 o;
        float dx;
        dx = q4.x - z4.x; o.x = z4.x + dx; acc += (double)dx * dx;
        dx = q4.y - z4.y; o.y = z4.y + dx; acc += (double)dx * dx;
        dx = q4.z - z4.z; o.z = z4.z + dx; acc += (double)dx * dx;
        dx = q4.w - z4.w; o.w = z4.w + dx; acc += (double)dx * dx;
        *(float4*)&out0[(size_t)row * D_DIM + d4 * 4] = o;
    }
    for (int m = 32; m >= 1; m >>= 1) acc += __shfl_xor(acc, m);
    __shared__ double sd[4];
    if ((tid & 63) == 0) sd[tid >> 6] = acc;
    __syncthreads();
    if (tid == 0) partials[blockIdx.x] = (sd[0] + sd[1]) + (sd[2] + sd[3]);
}

__global__ void finalize_kernel(const double* __restrict__ partials, float* __restrict__ out_loss) {
    __shared__ double sd[256];
    const int tid = threadIdx.x;
    double a = 0.0;
    for (int i = tid; i < 2048; i += 256) a += partials[i];
    sd[tid] = a;
    __syncthreads();
    for (int s = 128; s > 0; s >>= 1) {
        if (tid < s) sd[tid] += sd[tid + s];
        __syncthreads();
    }
    if (tid == 0) {
        double m = sd[0] / 16777216.0;
        out_loss[0] = (float)(m + 0.25 * m);   // codebook + BETA*commit = 1.25*mean
    }
}

extern "C" void kernel_launch(void* const* d_in, const int* in_sizes, int n_in,
                              void* d_out, int out_size, void* d_ws, size_t ws_size,
                              hipStream_t stream) {
    const float* z = (const float*)d_in[0];
    const float* emb = (const float*)d_in[1];
    float* out0 = (float*)d_out;
    float* out_loss = out0 + (size_t)N_ROWS * D_DIM;
    float* out_idx = out_loss + 1;

    char* ws = (char*)d_ws;
    float* rownorm = (float*)ws;
    float* cvec = (float*)(ws + 262144);
    double* partials = (double*)(ws + 278528);

    norm_kernel<<<N_ROWS / 64, 256, 0, stream>>>(z, rownorm);
    norm_kernel<<<K_CODES / 64, 256, 0, stream>>>(emb, cvec);
    phaseA_kernel<<<N_ROWS / TN, 256, 0, stream>>>(z, emb, rownorm, cvec, out_idx);
    writeback_kernel<<<N_ROWS / 32, 256, 0, stream>>>(z, emb, out_idx, out0, partials);
    finalize_kernel<<<1, 256, 0, stream>>>(partials, out_loss);
}

// Round 4
// 1031.628 us; speedup vs baseline: 1.8033x; 1.8033x over previous
//
#include <hip/hip_runtime.h>

#define N_ROWS 65536
#define K_CODES 4096
#define D_DIM 256
#define MARGIN_BF 1.0e-4f
#define LDSZ 264   // padded z-plane stride in bf16 elems (528 B): conflict-free A-frag reads

typedef __attribute__((ext_vector_type(8))) short bf16x8;
typedef __attribute__((ext_vector_type(4))) float f32x4;

// ---------------- ws layout ----------------
// [0]        float  rownorm[65536]      256 KB
// [262144]   float  cvec[4096]           16 KB
// [278528]   ushort emb_hi[4096*256]      2 MB
// [2375680]  int    flagcnt
// [2375936]  int    flaglist[65536]     256 KB
// [2638080]  u64    rescored[65536]     512 KB
// [3162368]  double partials[2048]       16 KB

static __device__ __forceinline__ unsigned short f32_to_bf16_rne(float f) {
    unsigned int u = __float_as_uint(f);
    return (unsigned short)((u + 0x7fffu + ((u >> 16) & 1u)) >> 16);
}

// ---------------- norms: f64 sum of f32 squares, rounded once (verified r2) ----------------
__global__ __launch_bounds__(256) void norm_kernel(const float* __restrict__ src,
                                                   float* __restrict__ dst) {
    int row = blockIdx.x * 64 + (threadIdx.x >> 2);
    int q = threadIdx.x & 3;
    const float* p = src + (size_t)row * D_DIM;
    double acc = 0.0;
#pragma unroll 4
    for (int it = 0; it < 16; ++it) {
        float4 v = *(const float4*)&p[(q + 4 * it) * 4];
        float a = v.x * v.x, b = v.y * v.y, c = v.z * v.z, d = v.w * v.w;
        acc += (double)a; acc += (double)b; acc += (double)c; acc += (double)d;
    }
    acc += __shfl_xor(acc, 1);
    acc += __shfl_xor(acc, 2);
    if (q == 0) dst[row] = (float)acc;
}

// ---------------- emb -> bf16 hi plane ----------------
__global__ __launch_bounds__(256) void cvt_emb_kernel(const float* __restrict__ emb,
                                                      unsigned short* __restrict__ emb_hi) {
    int i = blockIdx.x * 256 + threadIdx.x;   // float4 unit, 262144 total
    float4 v = *(const float4*)&emb[(size_t)i * 4];
    ushort4 h;
    h.x = f32_to_bf16_rne(v.x);
    h.y = f32_to_bf16_rne(v.y);
    h.z = f32_to_bf16_rne(v.z);
    h.w = f32_to_bf16_rne(v.w);
    *(ushort4*)&emb_hi[(size_t)i * 4] = h;
}

// ---------------- phase B: 2-pass bf16 MFMA GEMM-argmin ----------------
__global__ __launch_bounds__(256, 1) void phaseB_kernel(
        const float* __restrict__ z, const unsigned short* __restrict__ emb_hi,
        const float* __restrict__ cvec, float* __restrict__ out_idx,
        int* __restrict__ flagcnt, int* __restrict__ flaglist) {
    __shared__ unsigned short zhi[64 * LDSZ];          // 33792 B
    __shared__ unsigned short zlo[64 * LDSZ];          // 33792 B
    __shared__ unsigned short ebuf[2][256 * 64];       // 2 x 32768 B  (total 133120 B)

    const int tid = threadIdx.x;
    const int lane = tid & 63;
    const int w = tid >> 6;        // wave 0..3 -> code strip w*64 within each 256-tile
    const int l15 = lane & 15;
    const int l4 = lane >> 4;
    const int rowbase = blockIdx.x * 64;

    // ---- stage z -> hi/lo bf16 planes (once per block) ----
#pragma unroll
    for (int i = 0; i < 16; ++i) {
        int u = i * 256 + tid;            // float4 unit: 64 rows x 64
        int row = u >> 6, d4 = u & 63;
        float4 v = *(const float4*)&z[(size_t)(rowbase + row) * D_DIM + d4 * 4];
        ushort4 h, lo;
        h.x = f32_to_bf16_rne(v.x); lo.x = f32_to_bf16_rne(v.x - __uint_as_float((unsigned)h.x << 16));
        h.y = f32_to_bf16_rne(v.y); lo.y = f32_to_bf16_rne(v.y - __uint_as_float((unsigned)h.y << 16));
        h.z = f32_to_bf16_rne(v.z); lo.z = f32_to_bf16_rne(v.z - __uint_as_float((unsigned)h.z << 16));
        h.w = f32_to_bf16_rne(v.w); lo.w = f32_to_bf16_rne(v.w - __uint_as_float((unsigned)h.w << 16));
        *(ushort4*)&zhi[row * LDSZ + d4 * 4] = h;
        *(ushort4*)&zlo[row * LDSZ + d4 * 4] = lo;
    }

    float m1[16], m2[16];
    int i1[16];
#pragma unroll
    for (int s = 0; s < 16; ++s) { m1[s] = 3.4e38f; m2[s] = 3.4e38f; i1[s] = 0; }

    uint4 ld[8];
    // prologue: stage chunk 0 (kb=0, db=0) into ebuf[0], write-side XOR swizzle
#pragma unroll
    for (int i = 0; i < 8; ++i) {
        int u = i * 256 + tid;            // 16B unit, 2048 per chunk
        int code = u >> 3, sub = u & 7;
        ld[i] = *(const uint4*)&emb_hi[(size_t)code * 256 + sub * 8];
    }
#pragma unroll
    for (int i = 0; i < 8; ++i) {
        int u = i * 256 + tid;
        int code = u >> 3;
        int phys = (u * 16) ^ ((code & 7) << 4);
        *(uint4*)((char*)&ebuf[0][0] + phys) = ld[i];
    }

    f32x4 acc[4][4];

#pragma unroll 2
    for (int c = 0; c < 64; ++c) {
        const int kb = c >> 2, db = c & 3;
        __syncthreads();   // ebuf[c&1] staged; previous reads complete

        if (c < 63) {      // issue global loads for chunk c+1 (overlap with MFMA below)
            int kb1 = (c + 1) >> 2, db1 = (c + 1) & 3;
#pragma unroll
            for (int i = 0; i < 8; ++i) {
                int u = i * 256 + tid;
                int code = u >> 3, sub = u & 7;
                ld[i] = *(const uint4*)&emb_hi[(size_t)(kb1 * 256 + code) * 256 + db1 * 64 + sub * 8];
            }
        }

        if (db == 0) {
#pragma unroll
            for (int rf = 0; rf < 4; ++rf)
#pragma unroll
                for (int cf = 0; cf < 4; ++cf) acc[rf][cf] = (f32x4){0.f, 0.f, 0.f, 0.f};
        }

        const unsigned short* eb = ebuf[c & 1];
#pragma unroll
        for (int ds = 0; ds < 2; ++ds) {
            const int koff = db * 64 + ds * 32 + l4 * 8;
            bf16x8 ahi[4], alo[4], bb[4];
#pragma unroll
            for (int rf = 0; rf < 4; ++rf) {
                ahi[rf] = *(const bf16x8*)&zhi[(rf * 16 + l15) * LDSZ + koff];
                alo[rf] = *(const bf16x8*)&zlo[(rf * 16 + l15) * LDSZ + koff];
            }
#pragma unroll
            for (int cf = 0; cf < 4; ++cf) {
                int cl = w * 64 + cf * 16 + l15;               // code within 256-tile
                int lin = cl * 128 + (ds * 32 + l4 * 8) * 2;
                int phys = lin ^ ((cl & 7) << 4);
                bb[cf] = *(const bf16x8*)((const char*)eb + phys);
            }
#pragma unroll
            for (int cf = 0; cf < 4; ++cf)
#pragma unroll
                for (int rf = 0; rf < 4; ++rf) {
                    acc[rf][cf] = __builtin_amdgcn_mfma_f32_16x16x32_bf16(ahi[rf], bb[cf], acc[rf][cf], 0, 0, 0);
                    acc[rf][cf] = __builtin_amdgcn_mfma_f32_16x16x32_bf16(alo[rf], bb[cf], acc[rf][cf], 0, 0, 0);
                }
        }

        if (c < 63) {      // commit staged chunk c+1 (loads had MFMA time to land)
#pragma unroll
            for (int i = 0; i < 8; ++i) {
                int u = i * 256 + tid;
                int code = u >> 3;
                int phys = (u * 16) ^ ((code & 7) << 4);
                *(uint4*)((char*)&ebuf[(c + 1) & 1][0] + phys) = ld[i];
            }
        }

        if (db == 3) {     // epilogue: per-wave top-2 over this kb's strip codes
#pragma unroll
            for (int cf = 0; cf < 4; ++cf) {
                int codeg = kb * 256 + w * 64 + cf * 16 + l15;
                float ck = cvec[codeg];
#pragma unroll
                for (int rf = 0; rf < 4; ++rf)
#pragma unroll
                    for (int j = 0; j < 4; ++j) {
                        float d = fmaf(-2.0f, acc[rf][cf][j], ck);   // row-constant ||z||^2 dropped
                        const int s = rf * 4 + j;
                        bool lt = d < m1[s];
                        m2[s] = fminf(m2[s], fmaxf(d, m1[s]));
                        i1[s] = lt ? codeg : i1[s];
                        m1[s] = fminf(m1[s], d);
                    }
            }
        }
    }

    // ---- per-wave merge across the 16 column-lanes ----
    __syncthreads();                       // all MFMA/LDS reads done; ebuf reusable
    float* m1s = (float*)&ebuf[0][0];      // [4][64]
    float* m2s = m1s + 256;                // [4][64]
    int*   i1s = (int*)(m2s + 256);        // [4][64]
#pragma unroll
    for (int s = 0; s < 16; ++s) {
        float a1 = m1[s], a2 = m2[s];
        int ai = i1[s];
        for (int msk = 8; msk >= 1; msk >>= 1) {
            float b1 = __shfl_xor(a1, msk);
            float b2 = __shfl_xor(a2, msk);
            int   bi = __shfl_xor(ai, msk);
            float hi = fmaxf(a1, b1);
            a2 = fminf(fminf(a2, b2), hi);
            if (b1 < a1 || (b1 == a1 && bi < ai)) { a1 = b1; ai = bi; }
        }
        if (l15 == 0) {
            int rloc = (s >> 2) * 16 + l4 * 4 + (s & 3);   // row within block, 0..63
            m1s[w * 64 + rloc] = a1;
            m2s[w * 64 + rloc] = a2;
            i1s[w * 64 + rloc] = ai;
        }
    }
    __syncthreads();

    // ---- cross-wave merge: waves hold DISJOINT code subsets, must reduce ----
    if (tid < 64) {
        float b1 = 3.4e38f, b2 = 3.4e38f;
        int bi = 0;
#pragma unroll
        for (int ww = 0; ww < 4; ++ww) {
            float c1 = m1s[ww * 64 + tid];
            float c2 = m2s[ww * 64 + tid];
            int ci = i1s[ww * 64 + tid];
            float hi = fmaxf(b1, c1);
            b2 = fminf(fminf(b2, c2), hi);
            if (c1 < b1 || (c1 == b1 && ci < bi)) { b1 = c1; bi = ci; }
        }
        out_idx[rowbase + tid] = (float)bi;
        if (b2 - b1 < MARGIN_BF) {
            int p = atomicAdd(flagcnt, 1);
            flaglist[p] = rowbase + tid;
        }
    }
}

// ---------------- exact f32 rescore (bit-identical to verified r2 chain) ----------------
__global__ __launch_bounds__(256) void rescore_kernel(
        const float* __restrict__ z, const float* __restrict__ emb,
        const float* __restrict__ rownorm, const float* __restrict__ cvec,
        const int* __restrict__ flagcnt, const int* __restrict__ flaglist,
        unsigned long long* __restrict__ rescored) {
    __shared__ float zs[16][256];
    __shared__ float sa[16];
    __shared__ int srow[16];
    const int tid = threadIdx.x;
    const int cnt = *flagcnt;
    const int nu = ((cnt + 15) >> 4) << 3;   // ceil(cnt/16) row-groups x 8 code-splits
    for (int uu = blockIdx.x; uu < nu; uu += gridDim.x) {
        int rg = uu >> 3, ks = uu & 7;
        __syncthreads();                      // previous unit done with zs/srow
        if (tid < 16) {
            int fi = rg * 16 + tid;
            int row = flaglist[fi < cnt ? fi : 0];
            srow[tid] = row;
            sa[tid] = rownorm[row];
        }
        __syncthreads();
#pragma unroll
        for (int i = 0; i < 4; ++i) {
            int u = i * 256 + tid;            // 1024 float4 units
            int r = u >> 6, d4 = u & 63;
            *(float4*)&zs[r][d4 * 4] = *(const float4*)&z[(size_t)srow[r] * D_DIM + d4 * 4];
        }
        __syncthreads();

        const int c0 = ks * 512 + tid;
        const int c1 = c0 + 256;
        float acc0[16], acc1[16];
#pragma unroll
        for (int r = 0; r < 16; ++r) { acc0[r] = 0.f; acc1[r] = 0.f; }

        for (int ch = 0; ch < 8; ++ch) {      // 32 d per chunk, d ascending overall
            float4 e0[8], e1[8];
#pragma unroll
            for (int q = 0; q < 8; ++q) {
                e0[q] = *(const float4*)&emb[(size_t)c0 * D_DIM + ch * 32 + q * 4];
                e1[q] = *(const float4*)&emb[(size_t)c1 * D_DIM + ch * 32 + q * 4];
            }
#pragma unroll
            for (int r = 0; r < 16; ++r)
#pragma unroll
                for (int q = 0; q < 8; ++q) {
                    float4 zf = *(const float4*)&zs[r][ch * 32 + q * 4];   // LDS broadcast
                    acc0[r] = fmaf(zf.x, e0[q].x, acc0[r]);
                    acc0[r] = fmaf(zf.y, e0[q].y, acc0[r]);
                    acc0[r] = fmaf(zf.z, e0[q].z, acc0[r]);
                    acc0[r] = fmaf(zf.w, e0[q].w, acc0[r]);
                    acc1[r] = fmaf(zf.x, e1[q].x, acc1[r]);
                    acc1[r] = fmaf(zf.y, e1[q].y, acc1[r]);
                    acc1[r] = fmaf(zf.z, e1[q].z, acc1[r]);
                    acc1[r] = fmaf(zf.w, e1[q].w, acc1[r]);
                }
        }
        const float ck0 = cvec[c0], ck1 = cvec[c1];
#pragma unroll
        for (int r = 0; r < 16; ++r) {
            float d0 = __fadd_rn(__fsub_rn(sa[r], __fmul_rn(2.0f, acc0[r])), ck0);
            float d1 = __fadd_rn(__fsub_rn(sa[r], __fmul_rn(2.0f, acc1[r])), ck1);
            unsigned long long p0 = ((unsigned long long)__float_as_uint(d0) << 32) | (unsigned)c0;
            unsigned long long p1 = ((unsigned long long)__float_as_uint(d1) << 32) | (unsigned)c1;
            unsigned long long pm = p0 < p1 ? p0 : p1;
            for (int msk = 32; msk >= 1; msk >>= 1) {
                unsigned long long qv = __shfl_xor(pm, msk);
                pm = qv < pm ? qv : pm;
            }
            if ((tid & 63) == 0) atomicMin(&rescored[srow[r]], pm);
        }
    }
}

__global__ void fixup_kernel(const int* __restrict__ flagcnt, const int* __restrict__ flaglist,
                             const unsigned long long* __restrict__ rescored,
                             float* __restrict__ out_idx) {
    const int cnt = *flagcnt;
    for (int i = blockIdx.x * 256 + threadIdx.x; i < cnt; i += 256 * 64) {
        int row = flaglist[i];
        out_idx[row] = (float)(unsigned)(rescored[row] & 0xffffffffull);
    }
}

// ---------------- writeback z_q_st + loss partials (verified r2) ----------------
__global__ __launch_bounds__(256) void writeback_kernel(
        const float* __restrict__ z, const float* __restrict__ emb,
        const float* __restrict__ out_idx, float* __restrict__ out0,
        double* __restrict__ partials) {
    const int tid = threadIdx.x;
    const int base = blockIdx.x * 32;
    double acc = 0.0;
    for (int g = 0; g < 8; ++g) {
        int row = base + g * 4 + (tid >> 6);
        int d4 = tid & 63;
        int idx = (int)out_idx[row];
        float4 q4 = *(const float4*)&emb[(size_t)idx * D_DIM + d4 * 4];
        float4 z4 = *(const float4*)&z[(size_t)row * D_DIM + d4 * 4];
        float4 o;
        float dx;
        dx = q4.x - z4.x; o.x = z4.x + dx; acc += (double)dx * dx;
        dx = q4.y - z4.y; o.y = z4.y + dx; acc += (double)dx * dx;
        dx = q4.z - z4.z; o.z = z4.z + dx; acc += (double)dx * dx;
        dx = q4.w - z4.w; o.w = z4.w + dx; acc += (double)dx * dx;
        *(float4*)&out0[(size_t)row * D_DIM + d4 * 4] = o;
    }
    for (int m = 32; m >= 1; m >>= 1) acc += __shfl_xor(acc, m);
    __shared__ double sd[4];
    if ((tid & 63) == 0) sd[tid >> 6] = acc;
    __syncthreads();
    if (tid == 0) partials[blockIdx.x] = (sd[0] + sd[1]) + (sd[2] + sd[3]);
}

__global__ void finalize_kernel(const double* __restrict__ partials, float* __restrict__ out_loss) {
    __shared__ double sd[256];
    const int tid = threadIdx.x;
    double a = 0.0;
    for (int i = tid; i < 2048; i += 256) a += partials[i];
    sd[tid] = a;
    __syncthreads();
    for (int s = 128; s > 0; s >>= 1) {
        if (tid < s) sd[tid] += sd[tid + s];
        __syncthreads();
    }
    if (tid == 0) {
        double m = sd[0] / 16777216.0;
        out_loss[0] = (float)(m + 0.25 * m);
    }
}

extern "C" void kernel_launch(void* const* d_in, const int* in_sizes, int n_in,
                              void* d_out, int out_size, void* d_ws, size_t ws_size,
                              hipStream_t stream) {
    const float* z = (const float*)d_in[0];
    const float* emb = (const float*)d_in[1];
    float* out0 = (float*)d_out;
    float* out_loss = out0 + (size_t)N_ROWS * D_DIM;
    float* out_idx = out_loss + 1;

    char* ws = (char*)d_ws;
    float* rownorm = (float*)ws;
    float* cvec = (float*)(ws + 262144);
    unsigned short* emb_hi = (unsigned short*)(ws + 278528);
    int* flagcnt = (int*)(ws + 2375680);
    int* flaglist = (int*)(ws + 2375936);
    unsigned long long* rescored = (unsigned long long*)(ws + 2638080);
    double* partials = (double*)(ws + 3162368);

    hipMemsetAsync(flagcnt, 0, sizeof(int), stream);
    hipMemsetAsync(rescored, 0xFF, (size_t)N_ROWS * 8, stream);

    norm_kernel<<<N_ROWS / 64, 256, 0, stream>>>(z, rownorm);
    norm_kernel<<<K_CODES / 64, 256, 0, stream>>>(emb, cvec);
    cvt_emb_kernel<<<(K_CODES * D_DIM / 4) / 256, 256, 0, stream>>>(emb, emb_hi);
    phaseB_kernel<<<N_ROWS / 64, 256, 0, stream>>>(z, emb_hi, cvec, out_idx, flagcnt, flaglist);
    rescore_kernel<<<1024, 256, 0, stream>>>(z, emb, rownorm, cvec, flagcnt, flaglist, rescored);
    fixup_kernel<<<64, 256, 0, stream>>>(flagcnt, flaglist, rescored, out_idx);
    writeback_kernel<<<N_ROWS / 32, 256, 0, stream>>>(z, emb, out_idx, out0, partials);
    finalize_kernel<<<1, 256, 0, stream>>>(partials, out_loss);
}

// Round 5
// 570.932 us; speedup vs baseline: 3.2585x; 1.8069x over previous
//
#include <hip/hip_runtime.h>

#define N_ROWS 65536
#define K_CODES 4096
#define D_DIM 256
#define MARGIN_BF 6.0e-5f

typedef __attribute__((ext_vector_type(8))) _Float16 f16x8;
typedef __attribute__((ext_vector_type(4))) float f32x4;

// ---------------- ws layout ----------------
// [0]        float  rownorm[65536]      256 KB
// [262144]   float  cvec[4096]           16 KB
// [278528]   ushort emb_h[4096*256]       2 MB   (f16, scaled by 4096)
// [2375680]  int    flagcnt
// [2375936]  int    flaglist[65536]     256 KB
// [2638080]  u64    rescored[65536]     512 KB
// [3162368]  double partials[2048]       16 KB

union f16u { _Float16 h; unsigned short u; };

static __device__ __forceinline__ unsigned short f32_to_f16u(float f) {
    f16u c; c.h = (_Float16)f; return c.u;
}

// ---------------- norms: f64 sum of f32 squares, rounded once (verified r2) ----------------
__global__ __launch_bounds__(256) void norm_kernel(const float* __restrict__ src,
                                                   float* __restrict__ dst) {
    int row = blockIdx.x * 64 + (threadIdx.x >> 2);
    int q = threadIdx.x & 3;
    const float* p = src + (size_t)row * D_DIM;
    double acc = 0.0;
#pragma unroll 4
    for (int it = 0; it < 16; ++it) {
        float4 v = *(const float4*)&p[(q + 4 * it) * 4];
        float a = v.x * v.x, b = v.y * v.y, c = v.z * v.z, d = v.w * v.w;
        acc += (double)a; acc += (double)b; acc += (double)c; acc += (double)d;
    }
    acc += __shfl_xor(acc, 1);
    acc += __shfl_xor(acc, 2);
    if (q == 0) dst[row] = (float)acc;
}

// ---------------- emb -> f16 (x4096: keeps all values f16-normal) ----------------
__global__ __launch_bounds__(256) void cvt_emb_kernel(const float* __restrict__ emb,
                                                      unsigned short* __restrict__ emb_h) {
    int i = blockIdx.x * 256 + threadIdx.x;   // float4 unit, 262144 total
    float4 v = *(const float4*)&emb[(size_t)i * 4];
    ushort4 h;
    h.x = f32_to_f16u(v.x * 4096.0f);
    h.y = f32_to_f16u(v.y * 4096.0f);
    h.z = f32_to_f16u(v.z * 4096.0f);
    h.w = f32_to_f16u(v.w * 4096.0f);
    *(ushort4*)&emb_h[(size_t)i * 4] = h;
}

// ---------------- phase B: single-pass f16 MFMA GEMM-argmin, 2 blocks/CU ----------------
__global__ __launch_bounds__(256, 2) void phaseB_kernel(
        const float* __restrict__ z, const unsigned short* __restrict__ emb_h,
        const float* __restrict__ cvec, float* __restrict__ out_idx,
        int* __restrict__ flagcnt, int* __restrict__ flaglist) {
    __shared__ unsigned short zbuf[64 * 256];        // 32 KB, XOR-swizzled rows
    __shared__ unsigned short ebuf[2][256 * 32];     // 2 x 16 KB, XOR-swizzled

    const int tid = threadIdx.x;
    const int lane = tid & 63;
    const int w = tid >> 6;        // wave -> 64-code strip of each 256-code tile
    const int l15 = lane & 15, l4 = lane >> 4;
    const int rowbase = blockIdx.x * 64;

    // ---- stage z -> f16, swizzled: phys = (row*512 + d*2) ^ ((row&7)<<4) ----
#pragma unroll
    for (int i = 0; i < 16; ++i) {
        int u = i * 256 + tid;            // float4 unit: 64 rows x 64
        int row = u >> 6, d4 = u & 63;
        float4 v = *(const float4*)&z[(size_t)(rowbase + row) * D_DIM + d4 * 4];
        ushort4 h;
        h.x = f32_to_f16u(v.x); h.y = f32_to_f16u(v.y);
        h.z = f32_to_f16u(v.z); h.w = f32_to_f16u(v.w);
        int phys = (row * 512 + d4 * 8) ^ ((row & 7) << 4);
        *(ushort4*)((char*)zbuf + phys) = h;
    }

    // ---- prologue: stage chunk 0 (code-tile 0, d-slice 0) ----
    uint4 ld[4];
#pragma unroll
    for (int i = 0; i < 4; ++i) {
        int u = i * 256 + tid;            // 16B unit: 256 codes x 4
        int code = u >> 2, sub = u & 3;
        ld[i] = *(const uint4*)&emb_h[(size_t)code * 256 + sub * 8];
    }
#pragma unroll
    for (int i = 0; i < 4; ++i) {
        int u = i * 256 + tid;
        int code = u >> 2, sub = u & 3;
        int phys = (code * 64 + sub * 16) ^ ((code & 7) << 4);
        *(uint4*)((char*)&ebuf[0][0] + phys) = ld[i];
    }

    float m1[16], m2[16];
    int i1[16];
#pragma unroll
    for (int s = 0; s < 16; ++s) { m1[s] = 3.4e38f; m2[s] = 3.4e38f; i1[s] = 0; }

    f32x4 acc[4][4];

    for (int c = 0; c < 128; ++c) {       // 16 code-tiles x 8 d-slices
        const int kt = c >> 3, ds8 = c & 7;
        __syncthreads();                  // ebuf[c&1] ready; (c+1)-buffer reads done

        if (c < 127) {                    // issue next chunk's loads (land under MFMA)
            int kt1 = (c + 1) >> 3, ds1 = (c + 1) & 7;
#pragma unroll
            for (int i = 0; i < 4; ++i) {
                int u = i * 256 + tid;
                int code = u >> 2, sub = u & 3;
                ld[i] = *(const uint4*)&emb_h[(size_t)(kt1 * 256 + code) * 256 + ds1 * 32 + sub * 8];
            }
        }

        if (ds8 == 0) {
#pragma unroll
            for (int rf = 0; rf < 4; ++rf)
#pragma unroll
                for (int cf = 0; cf < 4; ++cf) acc[rf][cf] = (f32x4){0.f, 0.f, 0.f, 0.f};
        }

        f16x8 a[4], b[4];
#pragma unroll
        for (int rf = 0; rf < 4; ++rf) {
            int row = rf * 16 + l15;
            int phys = (row * 512 + ds8 * 64 + l4 * 16) ^ ((row & 7) << 4);
            a[rf] = *(const f16x8*)((const char*)zbuf + phys);
        }
#pragma unroll
        for (int cf = 0; cf < 4; ++cf) {
            int cl = w * 64 + cf * 16 + l15;
            int phys = (cl * 64 + l4 * 16) ^ ((cl & 7) << 4);
            b[cf] = *(const f16x8*)((const char*)&ebuf[c & 1][0] + phys);
        }
#pragma unroll
        for (int cf = 0; cf < 4; ++cf)
#pragma unroll
            for (int rf = 0; rf < 4; ++rf)
                acc[rf][cf] = __builtin_amdgcn_mfma_f32_16x16x32_f16(a[rf], b[cf], acc[rf][cf], 0, 0, 0);

        if (c < 127) {                    // commit next chunk into the other buffer
#pragma unroll
            for (int i = 0; i < 4; ++i) {
                int u = i * 256 + tid;
                int code = u >> 2, sub = u & 3;
                int phys = (code * 64 + sub * 16) ^ ((code & 7) << 4);
                *(uint4*)((char*)&ebuf[(c + 1) & 1][0] + phys) = ld[i];
            }
        }

        if (ds8 == 7) {                   // epilogue: top-2 over this 256-code tile
#pragma unroll
            for (int cf = 0; cf < 4; ++cf) {
                int codeg = kt * 256 + w * 64 + cf * 16 + l15;
                float ck = cvec[codeg];
#pragma unroll
                for (int rf = 0; rf < 4; ++rf)
#pragma unroll
                    for (int j = 0; j < 4; ++j) {
                        // acc = z.(4096 e); -2*dot = acc * -2^-11 (exact scale)
                        float d = fmaf(-4.8828125e-4f, acc[rf][cf][j], ck);
                        const int s = rf * 4 + j;
                        bool lt = d < m1[s];
                        m2[s] = fminf(m2[s], fmaxf(d, m1[s]));
                        i1[s] = lt ? codeg : i1[s];
                        m1[s] = fminf(m1[s], d);
                    }
            }
        }
    }

    // ---- per-wave merge across the 16 column-lanes (r4-verified) ----
    __syncthreads();
    float* m1s = (float*)&ebuf[0][0];      // [4][64]
    float* m2s = m1s + 256;                // [4][64]
    int*   i1s = (int*)(m2s + 256);        // [4][64]
#pragma unroll
    for (int s = 0; s < 16; ++s) {
        float a1 = m1[s], a2 = m2[s];
        int ai = i1[s];
        for (int msk = 8; msk >= 1; msk >>= 1) {
            float b1 = __shfl_xor(a1, msk);
            float b2 = __shfl_xor(a2, msk);
            int   bi = __shfl_xor(ai, msk);
            float hi = fmaxf(a1, b1);
            a2 = fminf(fminf(a2, b2), hi);
            if (b1 < a1 || (b1 == a1 && bi < ai)) { a1 = b1; ai = bi; }
        }
        if (l15 == 0) {
            int rloc = (s >> 2) * 16 + l4 * 4 + (s & 3);
            m1s[w * 64 + rloc] = a1;
            m2s[w * 64 + rloc] = a2;
            i1s[w * 64 + rloc] = ai;
        }
    }
    __syncthreads();

    // ---- cross-wave merge (waves hold disjoint code subsets) ----
    if (tid < 64) {
        float b1 = 3.4e38f, b2 = 3.4e38f;
        int bi = 0;
#pragma unroll
        for (int ww = 0; ww < 4; ++ww) {
            float c1 = m1s[ww * 64 + tid];
            float c2 = m2s[ww * 64 + tid];
            int ci = i1s[ww * 64 + tid];
            float hi = fmaxf(b1, c1);
            b2 = fminf(fminf(b2, c2), hi);
            if (c1 < b1 || (c1 == b1 && ci < bi)) { b1 = c1; bi = ci; }
        }
        out_idx[rowbase + tid] = (float)bi;
        if (b2 - b1 < MARGIN_BF) {
            int p = atomicAdd(flagcnt, 1);
            flaglist[p] = rowbase + tid;
        }
    }
}

// ---------------- exact f32 rescore (bit-identical to verified r2 chain) ----------------
__global__ __launch_bounds__(256) void rescore_kernel(
        const float* __restrict__ z, const float* __restrict__ emb,
        const float* __restrict__ rownorm, const float* __restrict__ cvec,
        const int* __restrict__ flagcnt, const int* __restrict__ flaglist,
        unsigned long long* __restrict__ rescored) {
    __shared__ float zs[16][256];
    __shared__ float sa[16];
    __shared__ int srow[16];
    const int tid = threadIdx.x;
    const int cnt = *flagcnt;
    const int nu = ((cnt + 15) >> 4) << 3;   // ceil(cnt/16) row-groups x 8 code-splits
    for (int uu = blockIdx.x; uu < nu; uu += gridDim.x) {
        int rg = uu >> 3, ks = uu & 7;
        __syncthreads();                      // previous unit done with zs/srow
        if (tid < 16) {
            int fi = rg * 16 + tid;
            int row = flaglist[fi < cnt ? fi : 0];
            srow[tid] = row;
            sa[tid] = rownorm[row];
        }
        __syncthreads();
#pragma unroll
        for (int i = 0; i < 4; ++i) {
            int u = i * 256 + tid;            // 1024 float4 units
            int r = u >> 6, d4 = u & 63;
            *(float4*)&zs[r][d4 * 4] = *(const float4*)&z[(size_t)srow[r] * D_DIM + d4 * 4];
        }
        __syncthreads();

        const int c0 = ks * 512 + tid;
        const int c1 = c0 + 256;
        float acc0[16], acc1[16];
#pragma unroll
        for (int r = 0; r < 16; ++r) { acc0[r] = 0.f; acc1[r] = 0.f; }

        for (int ch = 0; ch < 8; ++ch) {      // 32 d per chunk, d ascending overall
            float4 e0[8], e1[8];
#pragma unroll
            for (int q = 0; q < 8; ++q) {
                e0[q] = *(const float4*)&emb[(size_t)c0 * D_DIM + ch * 32 + q * 4];
                e1[q] = *(const float4*)&emb[(size_t)c1 * D_DIM + ch * 32 + q * 4];
            }
#pragma unroll
            for (int r = 0; r < 16; ++r)
#pragma unroll
                for (int q = 0; q < 8; ++q) {
                    float4 zf = *(const float4*)&zs[r][ch * 32 + q * 4];   // LDS broadcast
                    acc0[r] = fmaf(zf.x, e0[q].x, acc0[r]);
                    acc0[r] = fmaf(zf.y, e0[q].y, acc0[r]);
                    acc0[r] = fmaf(zf.z, e0[q].z, acc0[r]);
                    acc0[r] = fmaf(zf.w, e0[q].w, acc0[r]);
                    acc1[r] = fmaf(zf.x, e1[q].x, acc1[r]);
                    acc1[r] = fmaf(zf.y, e1[q].y, acc1[r]);
                    acc1[r] = fmaf(zf.z, e1[q].z, acc1[r]);
                    acc1[r] = fmaf(zf.w, e1[q].w, acc1[r]);
                }
        }
        const float ck0 = cvec[c0], ck1 = cvec[c1];
#pragma unroll
        for (int r = 0; r < 16; ++r) {
            float d0 = __fadd_rn(__fsub_rn(sa[r], __fmul_rn(2.0f, acc0[r])), ck0);
            float d1 = __fadd_rn(__fsub_rn(sa[r], __fmul_rn(2.0f, acc1[r])), ck1);
            unsigned long long p0 = ((unsigned long long)__float_as_uint(d0) << 32) | (unsigned)c0;
            unsigned long long p1 = ((unsigned long long)__float_as_uint(d1) << 32) | (unsigned)c1;
            unsigned long long pm = p0 < p1 ? p0 : p1;
            for (int msk = 32; msk >= 1; msk >>= 1) {
                unsigned long long qv = __shfl_xor(pm, msk);
                pm = qv < pm ? qv : pm;
            }
            if ((tid & 63) == 0) atomicMin(&rescored[srow[r]], pm);
        }
    }
}

__global__ void fixup_kernel(const int* __restrict__ flagcnt, const int* __restrict__ flaglist,
                             const unsigned long long* __restrict__ rescored,
                             float* __restrict__ out_idx) {
    const int cnt = *flagcnt;
    for (int i = blockIdx.x * 256 + threadIdx.x; i < cnt; i += 256 * 64) {
        int row = flaglist[i];
        out_idx[row] = (float)(unsigned)(rescored[row] & 0xffffffffull);
    }
}

// ---------------- writeback z_q_st + loss partials (verified r2) ----------------
__global__ __launch_bounds__(256) void writeback_kernel(
        const float* __restrict__ z, const float* __restrict__ emb,
        const float* __restrict__ out_idx, float* __restrict__ out0,
        double* __restrict__ partials) {
    const int tid = threadIdx.x;
    const int base = blockIdx.x * 32;
    double acc = 0.0;
    for (int g = 0; g < 8; ++g) {
        int row = base + g * 4 + (tid >> 6);
        int d4 = tid & 63;
        int idx = (int)out_idx[row];
        float4 q4 = *(const float4*)&emb[(size_t)idx * D_DIM + d4 * 4];
        float4 z4 = *(const float4*)&z[(size_t)row * D_DIM + d4 * 4];
        float4 o;
        float dx;
        dx = q4.x - z4.x; o.x = z4.x + dx; acc += (double)dx * dx;
        dx = q4.y - z4.y; o.y = z4.y + dx; acc += (double)dx * dx;
        dx = q4.z - z4.z; o.z = z4.z + dx; acc += (double)dx * dx;
        dx = q4.w - z4.w; o.w = z4.w + dx; acc += (double)dx * dx;
        *(float4*)&out0[(size_t)row * D_DIM + d4 * 4] = o;
    }
    for (int m = 32; m >= 1; m >>= 1) acc += __shfl_xor(acc, m);
    __shared__ double sd[4];
    if ((tid & 63) == 0) sd[tid >> 6] = acc;
    __syncthreads();
    if (tid == 0) partials[blockIdx.x] = (sd[0] + sd[1]) + (sd[2] + sd[3]);
}

__global__ void finalize_kernel(const double* __restrict__ partials, float* __restrict__ out_loss) {
    __shared__ double sd[256];
    const int tid = threadIdx.x;
    double a = 0.0;
    for (int i = tid; i < 2048; i += 256) a += partials[i];
    sd[tid] = a;
    __syncthreads();
    for (int s = 128; s > 0; s >>= 1) {
        if (tid < s) sd[tid] += sd[tid + s];
        __syncthreads();
    }
    if (tid == 0) {
        double m = sd[0] / 16777216.0;
        out_loss[0] = (float)(m + 0.25 * m);
    }
}

extern "C" void kernel_launch(void* const* d_in, const int* in_sizes, int n_in,
                              void* d_out, int out_size, void* d_ws, size_t ws_size,
                              hipStream_t stream) {
    const float* z = (const float*)d_in[0];
    const float* emb = (const float*)d_in[1];
    float* out0 = (float*)d_out;
    float* out_loss = out0 + (size_t)N_ROWS * D_DIM;
    float* out_idx = out_loss + 1;

    char* ws = (char*)d_ws;
    float* rownorm = (float*)ws;
    float* cvec = (float*)(ws + 262144);
    unsigned short* emb_h = (unsigned short*)(ws + 278528);
    int* flagcnt = (int*)(ws + 2375680);
    int* flaglist = (int*)(ws + 2375936);
    unsigned long long* rescored = (unsigned long long*)(ws + 2638080);
    double* partials = (double*)(ws + 3162368);

    hipMemsetAsync(flagcnt, 0, sizeof(int), stream);
    hipMemsetAsync(rescored, 0xFF, (size_t)N_ROWS * 8, stream);

    norm_kernel<<<N_ROWS / 64, 256, 0, stream>>>(z, rownorm);
    norm_kernel<<<K_CODES / 64, 256, 0, stream>>>(emb, cvec);
    cvt_emb_kernel<<<(K_CODES * D_DIM / 4) / 256, 256, 0, stream>>>(emb, emb_h);
    phaseB_kernel<<<N_ROWS / 64, 256, 0, stream>>>(z, emb_h, cvec, out_idx, flagcnt, flaglist);
    rescore_kernel<<<1024, 256, 0, stream>>>(z, emb, rownorm, cvec, flagcnt, flaglist, rescored);
    fixup_kernel<<<64, 256, 0, stream>>>(flagcnt, flaglist, rescored, out_idx);
    writeback_kernel<<<N_ROWS / 32, 256, 0, stream>>>(z, emb, out_idx, out0, partials);
    finalize_kernel<<<1, 256, 0, stream>>>(partials, out_loss);
}

// Round 6
// 447.288 us; speedup vs baseline: 4.1592x; 1.2764x over previous
//
#include <hip/hip_runtime.h>

#define N_ROWS 65536
#define K_CODES 4096
#define D_DIM 256
#define MARGIN_BF 6.0e-5f

typedef __attribute__((ext_vector_type(8))) _Float16 f16x8;
typedef __attribute__((ext_vector_type(4))) float f32x4;

typedef __attribute__((address_space(1))) unsigned int g_u32;
typedef __attribute__((address_space(3))) unsigned int l_u32;
// async global->LDS, 16B per lane; LDS dest = wave-uniform base + lane*16
#define GLOAD16(gp, lp) __builtin_amdgcn_global_load_lds((g_u32*)(gp), (l_u32*)(lp), 16, 0, 0)

// ---------------- ws layout ----------------
// [0]        float  rownorm[65536]      256 KB
// [262144]   float  cvec[4096]           16 KB
// [278528]   ushort emb_perm[4096*256]    2 MB   (f16 x4096, fragment-linear)
// [2375680]  int    flagcnt
// [2375936]  int    flaglist[65536]     256 KB
// [2638080]  u64    rescored[65536]     512 KB
// [3162368]  double partials[2048]       16 KB
// z_perm (32 MB, f16 fragment-linear) lives in d_out[0..8M floats) as scratch;
// writeback_kernel fully overwrites d_out afterwards (deterministic each replay).

union f16u { _Float16 h; unsigned short u; };

static __device__ __forceinline__ unsigned int pack2(float a, float b) {
    f16u x, y; x.h = (_Float16)a; y.h = (_Float16)b;
    return (unsigned)x.u | ((unsigned)y.u << 16);
}

// ---------------- norms: f64 sum of f32 squares, rounded once (verified r2) ----------------
__global__ __launch_bounds__(256) void norm_kernel(const float* __restrict__ src,
                                                   float* __restrict__ dst) {
    int row = blockIdx.x * 64 + (threadIdx.x >> 2);
    int q = threadIdx.x & 3;
    const float* p = src + (size_t)row * D_DIM;
    double acc = 0.0;
#pragma unroll 4
    for (int it = 0; it < 16; ++it) {
        float4 v = *(const float4*)&p[(q + 4 * it) * 4];
        float a = v.x * v.x, b = v.y * v.y, c = v.z * v.z, d = v.w * v.w;
        acc += (double)a; acc += (double)b; acc += (double)c; acc += (double)d;
    }
    acc += __shfl_xor(acc, 1);
    acc += __shfl_xor(acc, 2);
    if (q == 0) dst[row] = (float)acc;
}

// ---------------- emb -> f16(x4096), fragment-linear ----------------
// frag ft = ((kt*8+ds8)*16 + stripe)*64 + (l4*16+l15)
// holds emb[kt*256 + stripe*16 + l15][ds8*32 + l4*8 + 0..7] * 4096
__global__ __launch_bounds__(256) void cvt_emb_kernel(const float* __restrict__ emb,
                                                      unsigned short* __restrict__ emb_perm) {
    int ft = blockIdx.x * 256 + threadIdx.x;      // 131072 frags
    int lane = ft & 63, stripe = (ft >> 6) & 15, ds8 = (ft >> 10) & 7, kt = ft >> 13;
    int l15 = lane & 15, l4 = lane >> 4;
    int code = kt * 256 + stripe * 16 + l15;
    int d0 = ds8 * 32 + l4 * 8;
    const float* p = emb + (size_t)code * D_DIM + d0;
    float4 v0 = *(const float4*)p;
    float4 v1 = *(const float4*)(p + 4);
    uint4 o;
    o.x = pack2(v0.x * 4096.0f, v0.y * 4096.0f);
    o.y = pack2(v0.z * 4096.0f, v0.w * 4096.0f);
    o.z = pack2(v1.x * 4096.0f, v1.y * 4096.0f);
    o.w = pack2(v1.z * 4096.0f, v1.w * 4096.0f);
    *(uint4*)((char*)emb_perm + (size_t)ft * 16) = o;
}

// ---------------- z -> f16, fragment-linear per 64-row block ----------------
// frag ft = rb*2048 + ((ds8*4+rf)*4 + l4)*16 + l15
// holds z[rb*64 + rf*16 + l15][ds8*32 + l4*8 + 0..7]
__global__ __launch_bounds__(256) void cvt_z_kernel(const float* __restrict__ z,
                                                    unsigned short* __restrict__ z_perm) {
    int ft = blockIdx.x * 256 + threadIdx.x;      // 2097152 frags
    int rb = ft >> 11;
    int fi = ft & 2047;
    int ds8 = fi >> 8, rf = (fi >> 6) & 3, l4 = (fi >> 4) & 3, l15 = fi & 15;
    int row = rb * 64 + rf * 16 + l15;
    int d0 = ds8 * 32 + l4 * 8;
    const float* p = z + (size_t)row * D_DIM + d0;
    float4 v0 = *(const float4*)p;
    float4 v1 = *(const float4*)(p + 4);
    uint4 o;
    o.x = pack2(v0.x, v0.y);
    o.y = pack2(v0.z, v0.w);
    o.z = pack2(v1.x, v1.y);
    o.w = pack2(v1.z, v1.w);
    *(uint4*)((char*)z_perm + (size_t)ft * 16) = o;
}

// ---------------- phase B: f16 MFMA GEMM-argmin, lane-linear LDS ----------------
__global__ __launch_bounds__(256, 2) void phaseB_kernel(
        const unsigned short* __restrict__ z_perm, const unsigned short* __restrict__ emb_perm,
        const float* __restrict__ cvec, float* __restrict__ out_idx,
        int* __restrict__ flagcnt, int* __restrict__ flaglist) {
    __shared__ unsigned short zbuf[64 * 256];        // 32 KB fragment-linear
    __shared__ unsigned short ebuf[2][256 * 32];     // 2 x 16 KB fragment-linear

    const int tid = threadIdx.x;
    const int lane = tid & 63;
    const int w = tid >> 6;        // wave -> 64-code strip of each 256-code tile
    const int l15 = lane & 15, l4 = lane >> 4;
    const int rb = blockIdx.x;
    const int wb = tid & 192;      // w*64, wave-uniform

    const char* zsrc = (const char*)z_perm + (size_t)rb * 32768;
    const char* esrc = (const char*)emb_perm;

    // ---- prologue: async-stage z (8 groups) + e chunk 0 (4 groups) ----
#pragma unroll
    for (int i = 0; i < 8; ++i)
        GLOAD16(zsrc + (i * 256 + tid) * 16, (char*)zbuf + (i * 256 + wb) * 16);
#pragma unroll
    for (int i = 0; i < 4; ++i)
        GLOAD16(esrc + (i * 256 + tid) * 16, (char*)&ebuf[0][0] + (i * 256 + wb) * 16);

    float m1[16], m2[16];
    int i1[16];
#pragma unroll
    for (int s = 0; s < 16; ++s) { m1[s] = 3.4e38f; m2[s] = 3.4e38f; i1[s] = 0; }

    f32x4 acc[4][4];

    for (int c = 0; c < 128; ++c) {       // chunk = (kt = c>>3) x (ds8 = c&7)
        const int kt = c >> 3, ds8 = c & 7;
        __syncthreads();                  // drains vmcnt: chunk c staged; (c+1)-buf reads done

        if (c < 127) {                    // async-stage chunk c+1 (lands under MFMA)
#pragma unroll
            for (int i = 0; i < 4; ++i)
                GLOAD16(esrc + (size_t)(c + 1) * 16384 + (i * 256 + tid) * 16,
                        (char*)&ebuf[(c + 1) & 1][0] + (i * 256 + wb) * 16);
        }

        if (ds8 == 0) {
#pragma unroll
            for (int rf = 0; rf < 4; ++rf)
#pragma unroll
                for (int cf = 0; cf < 4; ++cf) acc[rf][cf] = (f32x4){0.f, 0.f, 0.f, 0.f};
        }

        f16x8 a[4], b[4];
#pragma unroll
        for (int rf = 0; rf < 4; ++rf)    // lane-contiguous: base + lane*16
            a[rf] = *(const f16x8*)((const char*)zbuf + ((ds8 * 4 + rf) * 64 + lane) * 16);
#pragma unroll
        for (int cf = 0; cf < 4; ++cf)
            b[cf] = *(const f16x8*)((const char*)&ebuf[c & 1][0] + ((w * 4 + cf) * 64 + lane) * 16);
#pragma unroll
        for (int cf = 0; cf < 4; ++cf)
#pragma unroll
            for (int rf = 0; rf < 4; ++rf)
                acc[rf][cf] = __builtin_amdgcn_mfma_f32_16x16x32_f16(a[rf], b[cf], acc[rf][cf], 0, 0, 0);

        if (ds8 == 7) {                   // epilogue: top-2 over this 256-code tile
#pragma unroll
            for (int cf = 0; cf < 4; ++cf) {
                int codeg = kt * 256 + w * 64 + cf * 16 + l15;
                float ck = cvec[codeg];
#pragma unroll
                for (int rf = 0; rf < 4; ++rf)
#pragma unroll
                    for (int j = 0; j < 4; ++j) {
                        // acc = z.(4096 e); -2*dot = acc * -2^-11 (exact scale)
                        float d = fmaf(-4.8828125e-4f, acc[rf][cf][j], ck);
                        const int s = rf * 4 + j;
                        bool lt = d < m1[s];
                        m2[s] = fminf(m2[s], fmaxf(d, m1[s]));
                        i1[s] = lt ? codeg : i1[s];
                        m1[s] = fminf(m1[s], d);
                    }
            }
        }
    }

    // ---- per-wave merge across the 16 column-lanes (r4-verified) ----
    __syncthreads();
    float* m1s = (float*)&ebuf[0][0];      // [4][64]
    float* m2s = m1s + 256;                // [4][64]
    int*   i1s = (int*)(m2s + 256);        // [4][64]
#pragma unroll
    for (int s = 0; s < 16; ++s) {
        float a1 = m1[s], a2 = m2[s];
        int ai = i1[s];
        for (int msk = 8; msk >= 1; msk >>= 1) {
            float b1 = __shfl_xor(a1, msk);
            float b2 = __shfl_xor(a2, msk);
            int   bi = __shfl_xor(ai, msk);
            float hi = fmaxf(a1, b1);
            a2 = fminf(fminf(a2, b2), hi);
            if (b1 < a1 || (b1 == a1 && bi < ai)) { a1 = b1; ai = bi; }
        }
        if (l15 == 0) {
            int rloc = (s >> 2) * 16 + l4 * 4 + (s & 3);
            m1s[w * 64 + rloc] = a1;
            m2s[w * 64 + rloc] = a2;
            i1s[w * 64 + rloc] = ai;
        }
    }
    __syncthreads();

    // ---- cross-wave merge (waves hold disjoint code subsets) ----
    if (tid < 64) {
        float b1 = 3.4e38f, b2 = 3.4e38f;
        int bi = 0;
#pragma unroll
        for (int ww = 0; ww < 4; ++ww) {
            float c1 = m1s[ww * 64 + tid];
            float c2 = m2s[ww * 64 + tid];
            int ci = i1s[ww * 64 + tid];
            float hi = fmaxf(b1, c1);
            b2 = fminf(fminf(b2, c2), hi);
            if (c1 < b1 || (c1 == b1 && ci < bi)) { b1 = c1; bi = ci; }
        }
        out_idx[rb * 64 + tid] = (float)bi;
        if (b2 - b1 < MARGIN_BF) {
            int p = atomicAdd(flagcnt, 1);
            flaglist[p] = rb * 64 + tid;
        }
    }
}

// ---------------- exact f32 rescore (bit-identical to verified r2 chain) ----------------
__global__ __launch_bounds__(256) void rescore_kernel(
        const float* __restrict__ z, const float* __restrict__ emb,
        const float* __restrict__ rownorm, const float* __restrict__ cvec,
        const int* __restrict__ flagcnt, const int* __restrict__ flaglist,
        unsigned long long* __restrict__ rescored) {
    __shared__ float zs[16][256];
    __shared__ float sa[16];
    __shared__ int srow[16];
    const int tid = threadIdx.x;
    const int cnt = *flagcnt;
    const int nu = ((cnt + 15) >> 4) << 3;   // ceil(cnt/16) row-groups x 8 code-splits
    for (int uu = blockIdx.x; uu < nu; uu += gridDim.x) {
        int rg = uu >> 3, ks = uu & 7;
        __syncthreads();                      // previous unit done with zs/srow
        if (tid < 16) {
            int fi = rg * 16 + tid;
            int row = flaglist[fi < cnt ? fi : 0];
            srow[tid] = row;
            sa[tid] = rownorm[row];
        }
        __syncthreads();
#pragma unroll
        for (int i = 0; i < 4; ++i) {
            int u = i * 256 + tid;            // 1024 float4 units
            int r = u >> 6, d4 = u & 63;
            *(float4*)&zs[r][d4 * 4] = *(const float4*)&z[(size_t)srow[r] * D_DIM + d4 * 4];
        }
        __syncthreads();

        const int c0 = ks * 512 + tid;
        const int c1 = c0 + 256;
        float acc0[16], acc1[16];
#pragma unroll
        for (int r = 0; r < 16; ++r) { acc0[r] = 0.f; acc1[r] = 0.f; }

        for (int ch = 0; ch < 8; ++ch) {      // 32 d per chunk, d ascending overall
            float4 e0[8], e1[8];
#pragma unroll
            for (int q = 0; q < 8; ++q) {
                e0[q] = *(const float4*)&emb[(size_t)c0 * D_DIM + ch * 32 + q * 4];
                e1[q] = *(const float4*)&emb[(size_t)c1 * D_DIM + ch * 32 + q * 4];
            }
#pragma unroll
            for (int r = 0; r < 16; ++r)
#pragma unroll
                for (int q = 0; q < 8; ++q) {
                    float4 zf = *(const float4*)&zs[r][ch * 32 + q * 4];   // LDS broadcast
                    acc0[r] = fmaf(zf.x, e0[q].x, acc0[r]);
                    acc0[r] = fmaf(zf.y, e0[q].y, acc0[r]);
                    acc0[r] = fmaf(zf.z, e0[q].z, acc0[r]);
                    acc0[r] = fmaf(zf.w, e0[q].w, acc0[r]);
                    acc1[r] = fmaf(zf.x, e1[q].x, acc1[r]);
                    acc1[r] = fmaf(zf.y, e1[q].y, acc1[r]);
                    acc1[r] = fmaf(zf.z, e1[q].z, acc1[r]);
                    acc1[r] = fmaf(zf.w, e1[q].w, acc1[r]);
                }
        }
        const float ck0 = cvec[c0], ck1 = cvec[c1];
#pragma unroll
        for (int r = 0; r < 16; ++r) {
            float d0 = __fadd_rn(__fsub_rn(sa[r], __fmul_rn(2.0f, acc0[r])), ck0);
            float d1 = __fadd_rn(__fsub_rn(sa[r], __fmul_rn(2.0f, acc1[r])), ck1);
            unsigned long long p0 = ((unsigned long long)__float_as_uint(d0) << 32) | (unsigned)c0;
            unsigned long long p1 = ((unsigned long long)__float_as_uint(d1) << 32) | (unsigned)c1;
            unsigned long long pm = p0 < p1 ? p0 : p1;
            for (int msk = 32; msk >= 1; msk >>= 1) {
                unsigned long long qv = __shfl_xor(pm, msk);
                pm = qv < pm ? qv : pm;
            }
            if ((tid & 63) == 0) atomicMin(&rescored[srow[r]], pm);
        }
    }
}

__global__ void fixup_kernel(const int* __restrict__ flagcnt, const int* __restrict__ flaglist,
                             const unsigned long long* __restrict__ rescored,
                             float* __restrict__ out_idx) {
    const int cnt = *flagcnt;
    for (int i = blockIdx.x * 256 + threadIdx.x; i < cnt; i += 256 * 64) {
        int row = flaglist[i];
        out_idx[row] = (float)(unsigned)(rescored[row] & 0xffffffffull);
    }
}

// ---------------- writeback z_q_st + loss partials (verified r2) ----------------
__global__ __launch_bounds__(256) void writeback_kernel(
        const float* __restrict__ z, const float* __restrict__ emb,
        const float* __restrict__ out_idx, float* __restrict__ out0,
        double* __restrict__ partials) {
    const int tid = threadIdx.x;
    const int base = blockIdx.x * 32;
    double acc = 0.0;
    for (int g = 0; g < 8; ++g) {
        int row = base + g * 4 + (tid >> 6);
        int d4 = tid & 63;
        int idx = (int)out_idx[row];
        float4 q4 = *(const float4*)&emb[(size_t)idx * D_DIM + d4 * 4];
        float4 z4 = *(const float4*)&z[(size_t)row * D_DIM + d4 * 4];
        float4 o;
        float dx;
        dx = q4.x - z4.x; o.x = z4.x + dx; acc += (double)dx * dx;
        dx = q4.y - z4.y; o.y = z4.y + dx; acc += (double)dx * dx;
        dx = q4.z - z4.z; o.z = z4.z + dx; acc += (double)dx * dx;
        dx = q4.w - z4.w; o.w = z4.w + dx; acc += (double)dx * dx;
        *(float4*)&out0[(size_t)row * D_DIM + d4 * 4] = o;
    }
    for (int m = 32; m >= 1; m >>= 1) acc += __shfl_xor(acc, m);
    __shared__ double sd[4];
    if ((tid & 63) == 0) sd[tid >> 6] = acc;
    __syncthreads();
    if (tid == 0) partials[blockIdx.x] = (sd[0] + sd[1]) + (sd[2] + sd[3]);
}

__global__ void finalize_kernel(const double* __restrict__ partials, float* __restrict__ out_loss) {
    __shared__ double sd[256];
    const int tid = threadIdx.x;
    double a = 0.0;
    for (int i = tid; i < 2048; i += 256) a += partials[i];
    sd[tid] = a;
    __syncthreads();
    for (int s = 128; s > 0; s >>= 1) {
        if (tid < s) sd[tid] += sd[tid + s];
        __syncthreads();
    }
    if (tid == 0) {
        double m = sd[0] / 16777216.0;
        out_loss[0] = (float)(m + 0.25 * m);
    }
}

extern "C" void kernel_launch(void* const* d_in, const int* in_sizes, int n_in,
                              void* d_out, int out_size, void* d_ws, size_t ws_size,
                              hipStream_t stream) {
    const float* z = (const float*)d_in[0];
    const float* emb = (const float*)d_in[1];
    float* out0 = (float*)d_out;
    float* out_loss = out0 + (size_t)N_ROWS * D_DIM;
    float* out_idx = out_loss + 1;

    char* ws = (char*)d_ws;
    float* rownorm = (float*)ws;
    float* cvec = (float*)(ws + 262144);
    unsigned short* emb_perm = (unsigned short*)(ws + 278528);
    int* flagcnt = (int*)(ws + 2375680);
    int* flaglist = (int*)(ws + 2375936);
    unsigned long long* rescored = (unsigned long long*)(ws + 2638080);
    double* partials = (double*)(ws + 3162368);

    // 32 MB z_perm scratch inside d_out (fully overwritten by writeback_kernel)
    unsigned short* z_perm = (unsigned short*)d_out;

    hipMemsetAsync(flagcnt, 0, sizeof(int), stream);
    hipMemsetAsync(rescored, 0xFF, (size_t)N_ROWS * 8, stream);

    norm_kernel<<<N_ROWS / 64, 256, 0, stream>>>(z, rownorm);
    norm_kernel<<<K_CODES / 64, 256, 0, stream>>>(emb, cvec);
    cvt_emb_kernel<<<512, 256, 0, stream>>>(emb, emb_perm);
    cvt_z_kernel<<<8192, 256, 0, stream>>>(z, z_perm);
    phaseB_kernel<<<N_ROWS / 64, 256, 0, stream>>>(z_perm, emb_perm, cvec, out_idx, flagcnt, flaglist);
    rescore_kernel<<<1024, 256, 0, stream>>>(z, emb, rownorm, cvec, flagcnt, flaglist, rescored);
    fixup_kernel<<<64, 256, 0, stream>>>(flagcnt, flaglist, rescored, out_idx);
    writeback_kernel<<<N_ROWS / 32, 256, 0, stream>>>(z, emb, out_idx, out0, partials);
    finalize_kernel<<<1, 256, 0, stream>>>(partials, out_loss);
}

// Round 7
// 418.542 us; speedup vs baseline: 4.4449x; 1.0687x over previous
//
#include <hip/hip_runtime.h>

#define N_ROWS 65536
#define K_CODES 4096
#define D_DIM 256
#define MARGIN_BF 6.0e-5f

typedef __attribute__((ext_vector_type(8))) _Float16 f16x8;
typedef __attribute__((ext_vector_type(4))) float f32x4;

typedef __attribute__((address_space(1))) unsigned int g_u32;
typedef __attribute__((address_space(3))) unsigned int l_u32;
// async global->LDS, 16B per lane; LDS dest = wave-uniform base + lane*16
#define GLOAD16(gp, lp) __builtin_amdgcn_global_load_lds((g_u32*)(gp), (l_u32*)(lp), 16, 0, 0)

// ---------------- ws layout (same footprint as r6) ----------------
// [0]        float  rownorm[65536]      256 KB
// [262144]   float  cvec[4096]           16 KB
// [278528]   ushort emb_perm[4096*256]    2 MB   (f16 x4096, per-wave chunk-linear)
// [2375680]  int    flagcnt
// [2375936]  int    flaglist[65536]     256 KB
// [2638080]  u64    rescored[65536]     512 KB
// [3162368]  double partials[2048]       16 KB
// z_perm (32 MB, f16 fragment-linear) lives in d_out[0..8M floats) as scratch;
// writeback_kernel fully overwrites d_out afterwards (deterministic each replay).

union f16u { _Float16 h; unsigned short u; };

static __device__ __forceinline__ unsigned int pack2(float a, float b) {
    f16u x, y; x.h = (_Float16)a; y.h = (_Float16)b;
    return (unsigned)x.u | ((unsigned)y.u << 16);
}

// ---------------- norms: f64 sum of f32 squares, rounded once (verified r2) ----------------
__global__ __launch_bounds__(256) void norm_kernel(const float* __restrict__ src,
                                                   float* __restrict__ dst) {
    int row = blockIdx.x * 64 + (threadIdx.x >> 2);
    int q = threadIdx.x & 3;
    const float* p = src + (size_t)row * D_DIM;
    double acc = 0.0;
#pragma unroll 4
    for (int it = 0; it < 16; ++it) {
        float4 v = *(const float4*)&p[(q + 4 * it) * 4];
        float a = v.x * v.x, b = v.y * v.y, c = v.z * v.z, d = v.w * v.w;
        acc += (double)a; acc += (double)b; acc += (double)c; acc += (double)d;
    }
    acc += __shfl_xor(acc, 1);
    acc += __shfl_xor(acc, 2);
    if (q == 0) dst[row] = (float)acc;
}

// ---------------- emb -> f16(x4096), per-wave chunk-linear ----------------
// 16B unit gid = ((c*8 + w)*2 + cf)*64 + lane,  c = kt*8+ds8  (128 chunks of 16KB)
// holds emb[kt*256 + w*32 + cf*16 + (lane&15)][ds8*32 + (lane>>4)*8 + 0..7] * 4096
__global__ __launch_bounds__(256) void cvt_emb_kernel(const float* __restrict__ emb,
                                                      unsigned short* __restrict__ emb_perm) {
    int gid = blockIdx.x * 256 + threadIdx.x;     // 131072 units
    int lane = gid & 63;
    int cf = (gid >> 6) & 1;
    int w = (gid >> 7) & 7;
    int c = gid >> 10;
    int kt = c >> 3, ds8 = c & 7;
    int code = kt * 256 + w * 32 + cf * 16 + (lane & 15);
    int d0 = ds8 * 32 + (lane >> 4) * 8;
    const float* p = emb + (size_t)code * D_DIM + d0;
    float4 v0 = *(const float4*)p;
    float4 v1 = *(const float4*)(p + 4);
    uint4 o;
    o.x = pack2(v0.x * 4096.0f, v0.y * 4096.0f);
    o.y = pack2(v0.z * 4096.0f, v0.w * 4096.0f);
    o.z = pack2(v1.x * 4096.0f, v1.y * 4096.0f);
    o.w = pack2(v1.z * 4096.0f, v1.w * 4096.0f);
    *(uint4*)((char*)emb_perm + (size_t)gid * 16) = o;
}

// ---------------- z -> f16, fragment-linear per 64-row block (verified r6) ----------------
// frag ft = rb*2048 + ((ds8*4+rf)*4 + l4)*16 + l15
// holds z[rb*64 + rf*16 + l15][ds8*32 + l4*8 + 0..7]
__global__ __launch_bounds__(256) void cvt_z_kernel(const float* __restrict__ z,
                                                    unsigned short* __restrict__ z_perm) {
    int ft = blockIdx.x * 256 + threadIdx.x;      // 2097152 frags
    int rb = ft >> 11;
    int fi = ft & 2047;
    int ds8 = fi >> 8, rf = (fi >> 6) & 3, l4 = (fi >> 4) & 3, l15 = fi & 15;
    int row = rb * 64 + rf * 16 + l15;
    int d0 = ds8 * 32 + l4 * 8;
    const float* p = z + (size_t)row * D_DIM + d0;
    float4 v0 = *(const float4*)p;
    float4 v1 = *(const float4*)(p + 4);
    uint4 o;
    o.x = pack2(v0.x, v0.y);
    o.y = pack2(v0.z, v0.w);
    o.z = pack2(v1.x, v1.y);
    o.w = pack2(v1.z, v1.w);
    *(uint4*)((char*)z_perm + (size_t)ft * 16) = o;
}

// ---------------- phase B: barrier-free per-wave-pipelined f16 MFMA argmin ----------------
// 8 waves = 8 code-strips; each wave: 64 rows (A in regs) x 32 codes; private
// 4-slot LDS ring staged 3 ahead via global_load_lds + counted vmcnt. No
// __syncthreads in the K-loop (zero cross-wave data).
__global__ __launch_bounds__(512, 2) void phaseB_kernel(
        const unsigned short* __restrict__ z_perm, const unsigned short* __restrict__ emb_perm,
        const float* __restrict__ cvec, float* __restrict__ out_idx,
        int* __restrict__ flagcnt, int* __restrict__ flaglist) {
    __shared__ unsigned short ebuf[8][4][1024];   // [wave][slot][2KB] = 64 KB

    const int tid = threadIdx.x;
    const int lane = tid & 63;
    const int w = tid >> 6;
    const int l15 = lane & 15, l4 = lane >> 4;
    const int rb = blockIdx.x;

    // ---- A (z) into registers: 32 frags = 128 VGPR, loaded once ----
    f16x8 A[8][4];
    {
        const char* zsrc = (const char*)z_perm + (size_t)rb * 32768 + lane * 16;
#pragma unroll
        for (int ds8 = 0; ds8 < 8; ++ds8)
#pragma unroll
            for (int rf = 0; rf < 4; ++rf)
                A[ds8][rf] = *(const f16x8*)(zsrc + (ds8 * 4 + rf) * 1024);
    }

    // ---- prologue: stage chunks 0..2 into slots 0..2 (own 2KB each) ----
    const char* ebase = (const char*)emb_perm + w * 2048 + lane * 16;
#pragma unroll
    for (int c = 0; c < 3; ++c)
#pragma unroll
        for (int cf = 0; cf < 2; ++cf)
            GLOAD16(ebase + c * 16384 + cf * 1024, &ebuf[w][c][cf * 512]);

    float m1[16], m2[16];
    int i1[16];
#pragma unroll
    for (int s = 0; s < 16; ++s) { m1[s] = 3.4e38f; m2[s] = 3.4e38f; i1[s] = 0; }

    const char* sp = ebase + 3 * 16384;   // global addr of chunk (c+3) at kt=0
    f32x4 acc[4][2];

    for (int kt = 0; kt < 16; ++kt) {
        // cvec for this kt (VMEM; oldest in window -> retires early, safe w/ vmcnt(6))
        const int kb = kt * 256 + w * 32;
        float ck0 = cvec[kb + l15];
        float ck1 = cvec[kb + 16 + l15];
#pragma unroll
        for (int rf = 0; rf < 4; ++rf) {
            acc[rf][0] = (f32x4){0.f, 0.f, 0.f, 0.f};
            acc[rf][1] = (f32x4){0.f, 0.f, 0.f, 0.f};
        }
        const int wrap = (kt == 15) ? 2097152 : 0;   // tail stages re-read chunks 0..2 (dead slots)
#pragma unroll
        for (int ds8 = 0; ds8 < 8; ++ds8) {
            // stage chunk c+3 into slot (c+3)&3 != c&3 (== slot(c-1), reads retired)
            {
                const char* g = sp + ds8 * 16384 - ((ds8 >= 5) ? wrap : 0);
                GLOAD16(g, &ebuf[w][(ds8 + 3) & 3][0]);
                GLOAD16(g + 1024, &ebuf[w][(ds8 + 3) & 3][512]);
            }
            // chunk c's 2 loads are (newest-7,8) in the FIFO -> vmcnt(6) retires them
            asm volatile("s_waitcnt vmcnt(6)" ::: "memory");
            f16x8 b0 = *(const f16x8*)&ebuf[w][ds8 & 3][lane * 8];
            f16x8 b1 = *(const f16x8*)&ebuf[w][ds8 & 3][512 + lane * 8];
#pragma unroll
            for (int rf = 0; rf < 4; ++rf) {
                acc[rf][0] = __builtin_amdgcn_mfma_f32_16x16x32_f16(A[ds8][rf], b0, acc[rf][0], 0, 0, 0);
                acc[rf][1] = __builtin_amdgcn_mfma_f32_16x16x32_f16(A[ds8][rf], b1, acc[rf][1], 0, 0, 0);
            }
        }
        sp += 131072;

        // ---- epilogue: top-2 over this kt's 32 codes (numerics identical to r6) ----
#pragma unroll
        for (int cf = 0; cf < 2; ++cf) {
            float ck = cf ? ck1 : ck0;
            int codeg = kb + cf * 16 + l15;
#pragma unroll
            for (int rf = 0; rf < 4; ++rf)
#pragma unroll
                for (int j = 0; j < 4; ++j) {
                    // acc = z.(4096 e); -2*dot = acc * -2^-11 (exact scale)
                    float d = fmaf(-4.8828125e-4f, acc[rf][cf][j], ck);
                    const int s = rf * 4 + j;
                    bool lt = d < m1[s];
                    m2[s] = fminf(m2[s], fmaxf(d, m1[s]));
                    i1[s] = lt ? codeg : i1[s];
                    m1[s] = fminf(m1[s], d);
                }
        }
    }

    // ---- per-wave merge across the 16 column-lanes (r4-verified) ----
    __syncthreads();                       // all waves done with ebuf (incl. staged tails)
    float* m1s = (float*)&ebuf[0][0][0];   // [8][64]
    float* m2s = m1s + 512;                // [8][64]
    int*   i1s = (int*)(m2s + 512);        // [8][64]
#pragma unroll
    for (int s = 0; s < 16; ++s) {
        float a1 = m1[s], a2 = m2[s];
        int ai = i1[s];
        for (int msk = 8; msk >= 1; msk >>= 1) {
            float b1 = __shfl_xor(a1, msk);
            float b2 = __shfl_xor(a2, msk);
            int   bi = __shfl_xor(ai, msk);
            float hi = fmaxf(a1, b1);
            a2 = fminf(fminf(a2, b2), hi);
            if (b1 < a1 || (b1 == a1 && bi < ai)) { a1 = b1; ai = bi; }
        }
        if (l15 == 0) {
            int rloc = (s >> 2) * 16 + l4 * 4 + (s & 3);   // row within block
            m1s[w * 64 + rloc] = a1;
            m2s[w * 64 + rloc] = a2;
            i1s[w * 64 + rloc] = ai;
        }
    }
    __syncthreads();

    // ---- cross-wave merge (8 disjoint code strips -> reduce) ----
    if (tid < 64) {
        float b1 = 3.4e38f, b2 = 3.4e38f;
        int bi = 0;
#pragma unroll
        for (int ww = 0; ww < 8; ++ww) {
            float c1 = m1s[ww * 64 + tid];
            float c2 = m2s[ww * 64 + tid];
            int ci = i1s[ww * 64 + tid];
            float hi = fmaxf(b1, c1);
            b2 = fminf(fminf(b2, c2), hi);
            if (c1 < b1 || (c1 == b1 && ci < bi)) { b1 = c1; bi = ci; }
        }
        out_idx[rb * 64 + tid] = (float)bi;
        if (b2 - b1 < MARGIN_BF) {
            int p = atomicAdd(flagcnt, 1);
            flaglist[p] = rb * 64 + tid;
        }
    }
}

// ---------------- exact f32 rescore (bit-identical to verified r2 chain) ----------------
__global__ __launch_bounds__(256) void rescore_kernel(
        const float* __restrict__ z, const float* __restrict__ emb,
        const float* __restrict__ rownorm, const float* __restrict__ cvec,
        const int* __restrict__ flagcnt, const int* __restrict__ flaglist,
        unsigned long long* __restrict__ rescored) {
    __shared__ float zs[16][256];
    __shared__ float sa[16];
    __shared__ int srow[16];
    const int tid = threadIdx.x;
    const int cnt = *flagcnt;
    const int nu = ((cnt + 15) >> 4) << 3;   // ceil(cnt/16) row-groups x 8 code-splits
    for (int uu = blockIdx.x; uu < nu; uu += gridDim.x) {
        int rg = uu >> 3, ks = uu & 7;
        __syncthreads();                      // previous unit done with zs/srow
        if (tid < 16) {
            int fi = rg * 16 + tid;
            int row = flaglist[fi < cnt ? fi : 0];
            srow[tid] = row;
            sa[tid] = rownorm[row];
        }
        __syncthreads();
#pragma unroll
        for (int i = 0; i < 4; ++i) {
            int u = i * 256 + tid;            // 1024 float4 units
            int r = u >> 6, d4 = u & 63;
            *(float4*)&zs[r][d4 * 4] = *(const float4*)&z[(size_t)srow[r] * D_DIM + d4 * 4];
        }
        __syncthreads();

        const int c0 = ks * 512 + tid;
        const int c1 = c0 + 256;
        float acc0[16], acc1[16];
#pragma unroll
        for (int r = 0; r < 16; ++r) { acc0[r] = 0.f; acc1[r] = 0.f; }

        for (int ch = 0; ch < 8; ++ch) {      // 32 d per chunk, d ascending overall
            float4 e0[8], e1[8];
#pragma unroll
            for (int q = 0; q < 8; ++q) {
                e0[q] = *(const float4*)&emb[(size_t)c0 * D_DIM + ch * 32 + q * 4];
                e1[q] = *(const float4*)&emb[(size_t)c1 * D_DIM + ch * 32 + q * 4];
            }
#pragma unroll
            for (int r = 0; r < 16; ++r)
#pragma unroll
                for (int q = 0; q < 8; ++q) {
                    float4 zf = *(const float4*)&zs[r][ch * 32 + q * 4];   // LDS broadcast
                    acc0[r] = fmaf(zf.x, e0[q].x, acc0[r]);
                    acc0[r] = fmaf(zf.y, e0[q].y, acc0[r]);
                    acc0[r] = fmaf(zf.z, e0[q].z, acc0[r]);
                    acc0[r] = fmaf(zf.w, e0[q].w, acc0[r]);
                    acc1[r] = fmaf(zf.x, e1[q].x, acc1[r]);
                    acc1[r] = fmaf(zf.y, e1[q].y, acc1[r]);
                    acc1[r] = fmaf(zf.z, e1[q].z, acc1[r]);
                    acc1[r] = fmaf(zf.w, e1[q].w, acc1[r]);
                }
        }
        const float ck0 = cvec[c0], ck1 = cvec[c1];
#pragma unroll
        for (int r = 0; r < 16; ++r) {
            float d0 = __fadd_rn(__fsub_rn(sa[r], __fmul_rn(2.0f, acc0[r])), ck0);
            float d1 = __fadd_rn(__fsub_rn(sa[r], __fmul_rn(2.0f, acc1[r])), ck1);
            unsigned long long p0 = ((unsigned long long)__float_as_uint(d0) << 32) | (unsigned)c0;
            unsigned long long p1 = ((unsigned long long)__float_as_uint(d1) << 32) | (unsigned)c1;
            unsigned long long pm = p0 < p1 ? p0 : p1;
            for (int msk = 32; msk >= 1; msk >>= 1) {
                unsigned long long qv = __shfl_xor(pm, msk);
                pm = qv < pm ? qv : pm;
            }
            if ((tid & 63) == 0) atomicMin(&rescored[srow[r]], pm);
        }
    }
}

__global__ void fixup_kernel(const int* __restrict__ flagcnt, const int* __restrict__ flaglist,
                             const unsigned long long* __restrict__ rescored,
                             float* __restrict__ out_idx) {
    const int cnt = *flagcnt;
    for (int i = blockIdx.x * 256 + threadIdx.x; i < cnt; i += 256 * 64) {
        int row = flaglist[i];
        out_idx[row] = (float)(unsigned)(rescored[row] & 0xffffffffull);
    }
}

// ---------------- writeback z_q_st + loss partials (verified r2) ----------------
__global__ __launch_bounds__(256) void writeback_kernel(
        const float* __restrict__ z, const float* __restrict__ emb,
        const float* __restrict__ out_idx, float* __restrict__ out0,
        double* __restrict__ partials) {
    const int tid = threadIdx.x;
    const int base = blockIdx.x * 32;
    double acc = 0.0;
    for (int g = 0; g < 8; ++g) {
        int row = base + g * 4 + (tid >> 6);
        int d4 = tid & 63;
        int idx = (int)out_idx[row];
        float4 q4 = *(const float4*)&emb[(size_t)idx * D_DIM + d4 * 4];
        float4 z4 = *(const float4*)&z[(size_t)row * D_DIM + d4 * 4];
        float4 o;
        float dx;
        dx = q4.x - z4.x; o.x = z4.x + dx; acc += (double)dx * dx;
        dx = q4.y - z4.y; o.y = z4.y + dx; acc += (double)dx * dx;
        dx = q4.z - z4.z; o.z = z4.z + dx; acc += (double)dx * dx;
        dx = q4.w - z4.w; o.w = z4.w + dx; acc += (double)dx * dx;
        *(float4*)&out0[(size_t)row * D_DIM + d4 * 4] = o;
    }
    for (int m = 32; m >= 1; m >>= 1) acc += __shfl_xor(acc, m);
    __shared__ double sd[4];
    if ((tid & 63) == 0) sd[tid >> 6] = acc;
    __syncthreads();
    if (tid == 0) partials[blockIdx.x] = (sd[0] + sd[1]) + (sd[2] + sd[3]);
}

__global__ void finalize_kernel(const double* __restrict__ partials, float* __restrict__ out_loss) {
    __shared__ double sd[256];
    const int tid = threadIdx.x;
    double a = 0.0;
    for (int i = tid; i < 2048; i += 256) a += partials[i];
    sd[tid] = a;
    __syncthreads();
    for (int s = 128; s > 0; s >>= 1) {
        if (tid < s) sd[tid] += sd[tid + s];
        __syncthreads();
    }
    if (tid == 0) {
        double m = sd[0] / 16777216.0;
        out_loss[0] = (float)(m + 0.25 * m);
    }
}

extern "C" void kernel_launch(void* const* d_in, const int* in_sizes, int n_in,
                              void* d_out, int out_size, void* d_ws, size_t ws_size,
                              hipStream_t stream) {
    const float* z = (const float*)d_in[0];
    const float* emb = (const float*)d_in[1];
    float* out0 = (float*)d_out;
    float* out_loss = out0 + (size_t)N_ROWS * D_DIM;
    float* out_idx = out_loss + 1;

    char* ws = (char*)d_ws;
    float* rownorm = (float*)ws;
    float* cvec = (float*)(ws + 262144);
    unsigned short* emb_perm = (unsigned short*)(ws + 278528);
    int* flagcnt = (int*)(ws + 2375680);
    int* flaglist = (int*)(ws + 2375936);
    unsigned long long* rescored = (unsigned long long*)(ws + 2638080);
    double* partials = (double*)(ws + 3162368);

    // 32 MB z_perm scratch inside d_out (fully overwritten by writeback_kernel)
    unsigned short* z_perm = (unsigned short*)d_out;

    hipMemsetAsync(flagcnt, 0, sizeof(int), stream);
    hipMemsetAsync(rescored, 0xFF, (size_t)N_ROWS * 8, stream);

    norm_kernel<<<N_ROWS / 64, 256, 0, stream>>>(z, rownorm);
    norm_kernel<<<K_CODES / 64, 256, 0, stream>>>(emb, cvec);
    cvt_emb_kernel<<<512, 256, 0, stream>>>(emb, emb_perm);
    cvt_z_kernel<<<8192, 256, 0, stream>>>(z, z_perm);
    phaseB_kernel<<<N_ROWS / 64, 512, 0, stream>>>(z_perm, emb_perm, cvec, out_idx, flagcnt, flaglist);
    rescore_kernel<<<1024, 256, 0, stream>>>(z, emb, rownorm, cvec, flagcnt, flaglist, rescored);
    fixup_kernel<<<64, 256, 0, stream>>>(flagcnt, flaglist, rescored, out_idx);
    writeback_kernel<<<N_ROWS / 32, 256, 0, stream>>>(z, emb, out_idx, out0, partials);
    finalize_kernel<<<1, 256, 0, stream>>>(partials, out_loss);
}

// Round 9
// 401.588 us; speedup vs baseline: 4.6325x; 1.0422x over previous
//
#include <hip/hip_runtime.h>

#define N_ROWS 65536
#define K_CODES 4096
#define D_DIM 256
#define MARGIN_BF 4.5e-5f

typedef __attribute__((ext_vector_type(8))) _Float16 f16x8;
typedef __attribute__((ext_vector_type(4))) float f32x4;

typedef __attribute__((address_space(1))) unsigned int g_u32;
typedef __attribute__((address_space(3))) unsigned int l_u32;
// async global->LDS, 16B per lane; LDS dest = wave-uniform base + lane*16
#define GLOAD16(gp, lp) __builtin_amdgcn_global_load_lds((g_u32*)(gp), (l_u32*)(lp), 16, 0, 0)

// ---------------- ws layout (same footprint as r7) ----------------
// [0]        float  rownorm[65536]      256 KB
// [262144]   float  cvec[4096]           16 KB
// [278528]   ushort emb_perm[4096*256]    2 MB   (f16 x4096, per-wave chunk-linear)
// [2375680]  int    flagcnt
// [2375936]  int    flaglist[65536]     256 KB
// [2638080]  u64    rescored[65536]     512 KB
// [3162368]  double partials[2048]       16 KB
// z_perm (32 MB, f16 fragment-linear) lives in d_out[0..8M floats) as scratch;
// writeback_kernel fully overwrites d_out afterwards (deterministic each replay).

union f16u { _Float16 h; unsigned short u; };

static __device__ __forceinline__ unsigned int pack2(float a, float b) {
    f16u x, y; x.h = (_Float16)a; y.h = (_Float16)b;
    return (unsigned)x.u | ((unsigned)y.u << 16);
}

// ---------------- norms: f64 sum of f32 squares, rounded once (verified r2) ----------------
__global__ __launch_bounds__(256) void norm_kernel(const float* __restrict__ src,
                                                   float* __restrict__ dst) {
    int row = blockIdx.x * 64 + (threadIdx.x >> 2);
    int q = threadIdx.x & 3;
    const float* p = src + (size_t)row * D_DIM;
    double acc = 0.0;
#pragma unroll 4
    for (int it = 0; it < 16; ++it) {
        float4 v = *(const float4*)&p[(q + 4 * it) * 4];
        float a = v.x * v.x, b = v.y * v.y, c = v.z * v.z, d = v.w * v.w;
        acc += (double)a; acc += (double)b; acc += (double)c; acc += (double)d;
    }
    acc += __shfl_xor(acc, 1);
    acc += __shfl_xor(acc, 2);
    if (q == 0) dst[row] = (float)acc;
}

// ---------------- emb -> f16(x4096), per-wave chunk-linear (verified r7) ----------------
__global__ __launch_bounds__(256) void cvt_emb_kernel(const float* __restrict__ emb,
                                                      unsigned short* __restrict__ emb_perm) {
    int gid = blockIdx.x * 256 + threadIdx.x;     // 131072 units
    int lane = gid & 63;
    int cf = (gid >> 6) & 1;
    int w = (gid >> 7) & 7;
    int c = gid >> 10;
    int kt = c >> 3, ds8 = c & 7;
    int code = kt * 256 + w * 32 + cf * 16 + (lane & 15);
    int d0 = ds8 * 32 + (lane >> 4) * 8;
    const float* p = emb + (size_t)code * D_DIM + d0;
    float4 v0 = *(const float4*)p;
    float4 v1 = *(const float4*)(p + 4);
    uint4 o;
    o.x = pack2(v0.x * 4096.0f, v0.y * 4096.0f);
    o.y = pack2(v0.z * 4096.0f, v0.w * 4096.0f);
    o.z = pack2(v1.x * 4096.0f, v1.y * 4096.0f);
    o.w = pack2(v1.z * 4096.0f, v1.w * 4096.0f);
    *(uint4*)((char*)emb_perm + (size_t)gid * 16) = o;
}

// ---------------- z -> f16, fragment-linear per 64-row block (verified r6) ----------------
__global__ __launch_bounds__(256) void cvt_z_kernel(const float* __restrict__ z,
                                                    unsigned short* __restrict__ z_perm) {
    int ft = blockIdx.x * 256 + threadIdx.x;      // 2097152 frags
    int rb = ft >> 11;
    int fi = ft & 2047;
    int ds8 = fi >> 8, rf = (fi >> 6) & 3, l4 = (fi >> 4) & 3, l15 = fi & 15;
    int row = rb * 64 + rf * 16 + l15;
    int d0 = ds8 * 32 + l4 * 8;
    const float* p = z + (size_t)row * D_DIM + d0;
    float4 v0 = *(const float4*)p;
    float4 v1 = *(const float4*)(p + 4);
    uint4 o;
    o.x = pack2(v0.x, v0.y);
    o.y = pack2(v0.z, v0.w);
    o.z = pack2(v1.x, v1.y);
    o.w = pack2(v1.z, v1.w);
    *(uint4*)((char*)z_perm + (size_t)ft * 16) = o;
}

// ---------------- phase B: barrier-free per-wave-pipelined f16 MFMA argmin (verified r7) ----
__global__ __launch_bounds__(512, 2) void phaseB_kernel(
        const unsigned short* __restrict__ z_perm, const unsigned short* __restrict__ emb_perm,
        const float* __restrict__ cvec, float* __restrict__ out_idx,
        int* __restrict__ flagcnt, int* __restrict__ flaglist) {
    __shared__ unsigned short ebuf[8][4][1024];   // [wave][slot][2KB] = 64 KB

    const int tid = threadIdx.x;
    const int lane = tid & 63;
    const int w = tid >> 6;
    const int l15 = lane & 15, l4 = lane >> 4;
    const int rb = blockIdx.x;

    // ---- A (z) into registers: 32 frags = 128 VGPR, loaded once ----
    f16x8 A[8][4];
    {
        const char* zsrc = (const char*)z_perm + (size_t)rb * 32768 + lane * 16;
#pragma unroll
        for (int ds8 = 0; ds8 < 8; ++ds8)
#pragma unroll
            for (int rf = 0; rf < 4; ++rf)
                A[ds8][rf] = *(const f16x8*)(zsrc + (ds8 * 4 + rf) * 1024);
    }

    // ---- prologue: stage chunks 0..2 into slots 0..2 (own 2KB each) ----
    const char* ebase = (const char*)emb_perm + w * 2048 + lane * 16;
#pragma unroll
    for (int c = 0; c < 3; ++c)
#pragma unroll
        for (int cf = 0; cf < 2; ++cf)
            GLOAD16(ebase + c * 16384 + cf * 1024, &ebuf[w][c][cf * 512]);

    float m1[16], m2[16];
    int i1[16];
#pragma unroll
    for (int s = 0; s < 16; ++s) { m1[s] = 3.4e38f; m2[s] = 3.4e38f; i1[s] = 0; }

    const char* sp = ebase + 3 * 16384;   // global addr of chunk (c+3) at kt=0
    f32x4 acc[4][2];

    for (int kt = 0; kt < 16; ++kt) {
        const int kb = kt * 256 + w * 32;
        float ck0 = cvec[kb + l15];
        float ck1 = cvec[kb + 16 + l15];
#pragma unroll
        for (int rf = 0; rf < 4; ++rf) {
            acc[rf][0] = (f32x4){0.f, 0.f, 0.f, 0.f};
            acc[rf][1] = (f32x4){0.f, 0.f, 0.f, 0.f};
        }
        const int wrap = (kt == 15) ? 2097152 : 0;   // tail stages re-read chunks 0..2 (dead slots)
#pragma unroll
        for (int ds8 = 0; ds8 < 8; ++ds8) {
            // stage chunk c+3 into slot (c+3)&3 != c&3 (== slot(c-1), reads retired)
            {
                const char* g = sp + ds8 * 16384 - ((ds8 >= 5) ? wrap : 0);
                GLOAD16(g, &ebuf[w][(ds8 + 3) & 3][0]);
                GLOAD16(g + 1024, &ebuf[w][(ds8 + 3) & 3][512]);
            }
            // chunk c's 2 loads are (newest-7,8) in the FIFO -> vmcnt(6) retires them
            asm volatile("s_waitcnt vmcnt(6)" ::: "memory");
            f16x8 b0 = *(const f16x8*)&ebuf[w][ds8 & 3][lane * 8];
            f16x8 b1 = *(const f16x8*)&ebuf[w][ds8 & 3][512 + lane * 8];
#pragma unroll
            for (int rf = 0; rf < 4; ++rf) {
                acc[rf][0] = __builtin_amdgcn_mfma_f32_16x16x32_f16(A[ds8][rf], b0, acc[rf][0], 0, 0, 0);
                acc[rf][1] = __builtin_amdgcn_mfma_f32_16x16x32_f16(A[ds8][rf], b1, acc[rf][1], 0, 0, 0);
            }
        }
        sp += 131072;

        // ---- epilogue: top-2 over this kt's 32 codes ----
#pragma unroll
        for (int cf = 0; cf < 2; ++cf) {
            float ck = cf ? ck1 : ck0;
            int codeg = kb + cf * 16 + l15;
#pragma unroll
            for (int rf = 0; rf < 4; ++rf)
#pragma unroll
                for (int j = 0; j < 4; ++j) {
                    // acc = z.(4096 e); -2*dot = acc * -2^-11 (exact scale)
                    float d = fmaf(-4.8828125e-4f, acc[rf][cf][j], ck);
                    const int s = rf * 4 + j;
                    bool lt = d < m1[s];
                    m2[s] = fminf(m2[s], fmaxf(d, m1[s]));
                    i1[s] = lt ? codeg : i1[s];
                    m1[s] = fminf(m1[s], d);
                }
        }
    }

    // ---- per-wave merge across the 16 column-lanes (r4-verified) ----
    __syncthreads();                       // all waves done with ebuf (incl. staged tails)
    float* m1s = (float*)&ebuf[0][0][0];   // [8][64]
    float* m2s = m1s + 512;                // [8][64]
    int*   i1s = (int*)(m2s + 512);        // [8][64]
#pragma unroll
    for (int s = 0; s < 16; ++s) {
        float a1 = m1[s], a2 = m2[s];
        int ai = i1[s];
        for (int msk = 8; msk >= 1; msk >>= 1) {
            float b1 = __shfl_xor(a1, msk);
            float b2 = __shfl_xor(a2, msk);
            int   bi = __shfl_xor(ai, msk);
            float hi = fmaxf(a1, b1);
            a2 = fminf(fminf(a2, b2), hi);
            if (b1 < a1 || (b1 == a1 && bi < ai)) { a1 = b1; ai = bi; }
        }
        if (l15 == 0) {
            int rloc = (s >> 2) * 16 + l4 * 4 + (s & 3);   // row within block
            m1s[w * 64 + rloc] = a1;
            m2s[w * 64 + rloc] = a2;
            i1s[w * 64 + rloc] = ai;
        }
    }
    __syncthreads();

    // ---- cross-wave merge (8 disjoint code strips -> reduce) ----
    if (tid < 64) {
        float b1 = 3.4e38f, b2 = 3.4e38f;
        int bi = 0;
#pragma unroll
        for (int ww = 0; ww < 8; ++ww) {
            float c1 = m1s[ww * 64 + tid];
            float c2 = m2s[ww * 64 + tid];
            int ci = i1s[ww * 64 + tid];
            float hi = fmaxf(b1, c1);
            b2 = fminf(fminf(b2, c2), hi);
            if (c1 < b1 || (c1 == b1 && ci < bi)) { b1 = c1; bi = ci; }
        }
        out_idx[rb * 64 + tid] = (float)bi;
        if (b2 - b1 < MARGIN_BF) {
            int p = atomicAdd(flagcnt, 1);
            flaglist[p] = rb * 64 + tid;
        }
    }
}

// ---------------- exact f32 rescore: 4 codes/thread (chain bit-identical to r2) ----------------
__global__ __launch_bounds__(256) void rescore_kernel(
        const float* __restrict__ z, const float* __restrict__ emb,
        const float* __restrict__ rownorm, const float* __restrict__ cvec,
        const int* __restrict__ flagcnt, const int* __restrict__ flaglist,
        unsigned long long* __restrict__ rescored) {
    __shared__ float zs[16][256];
    __shared__ float sa[16];
    __shared__ int srow[16];
    const int tid = threadIdx.x;
    const int cnt = *flagcnt;
    const int nu = ((cnt + 15) >> 4) << 2;   // ceil(cnt/16) row-groups x 4 code-splits
    for (int uu = blockIdx.x; uu < nu; uu += gridDim.x) {
        int rg = uu >> 2, ks = uu & 3;
        __syncthreads();                      // previous unit done with zs/srow
        if (tid < 16) {
            int fi = rg * 16 + tid;
            int row = flaglist[fi < cnt ? fi : 0];   // padding = a real flagged row
            srow[tid] = row;
            sa[tid] = rownorm[row];
        }
        __syncthreads();
#pragma unroll
        for (int i = 0; i < 4; ++i) {
            int u = i * 256 + tid;            // 1024 float4 units
            int r = u >> 6, d4 = u & 63;
            *(float4*)&zs[r][d4 * 4] = *(const float4*)&z[(size_t)srow[r] * D_DIM + d4 * 4];
        }
        __syncthreads();

        const int c0 = ks * 1024 + tid;       // codes c0 + {0,256,512,768}
        float acc[16][4];
#pragma unroll
        for (int r = 0; r < 16; ++r)
#pragma unroll
            for (int j = 0; j < 4; ++j) acc[r][j] = 0.f;

        for (int ch = 0; ch < 8; ++ch) {      // 32 d per chunk, d ascending overall
#pragma unroll
            for (int q = 0; q < 8; ++q) {
                float4 e0 = *(const float4*)&emb[(size_t)(c0      ) * D_DIM + ch * 32 + q * 4];
                float4 e1 = *(const float4*)&emb[(size_t)(c0 + 256) * D_DIM + ch * 32 + q * 4];
                float4 e2 = *(const float4*)&emb[(size_t)(c0 + 512) * D_DIM + ch * 32 + q * 4];
                float4 e3 = *(const float4*)&emb[(size_t)(c0 + 768) * D_DIM + ch * 32 + q * 4];
#pragma unroll
                for (int r = 0; r < 16; ++r) {
                    float4 zf = *(const float4*)&zs[r][ch * 32 + q * 4];   // LDS broadcast
                    acc[r][0] = fmaf(zf.x, e0.x, acc[r][0]);
                    acc[r][0] = fmaf(zf.y, e0.y, acc[r][0]);
                    acc[r][0] = fmaf(zf.z, e0.z, acc[r][0]);
                    acc[r][0] = fmaf(zf.w, e0.w, acc[r][0]);
                    acc[r][1] = fmaf(zf.x, e1.x, acc[r][1]);
                    acc[r][1] = fmaf(zf.y, e1.y, acc[r][1]);
                    acc[r][1] = fmaf(zf.z, e1.z, acc[r][1]);
                    acc[r][1] = fmaf(zf.w, e1.w, acc[r][1]);
                    acc[r][2] = fmaf(zf.x, e2.x, acc[r][2]);
                    acc[r][2] = fmaf(zf.y, e2.y, acc[r][2]);
                    acc[r][2] = fmaf(zf.z, e2.z, acc[r][2]);
                    acc[r][2] = fmaf(zf.w, e2.w, acc[r][2]);
                    acc[r][3] = fmaf(zf.x, e3.x, acc[r][3]);
                    acc[r][3] = fmaf(zf.y, e3.y, acc[r][3]);
                    acc[r][3] = fmaf(zf.z, e3.z, acc[r][3]);
                    acc[r][3] = fmaf(zf.w, e3.w, acc[r][3]);
                }
            }
        }
        const float ck0 = cvec[c0], ck1 = cvec[c0 + 256];
        const float ck2 = cvec[c0 + 512], ck3 = cvec[c0 + 768];
#pragma unroll
        for (int r = 0; r < 16; ++r) {
            float d0 = __fadd_rn(__fsub_rn(sa[r], __fmul_rn(2.0f, acc[r][0])), ck0);
            float d1 = __fadd_rn(__fsub_rn(sa[r], __fmul_rn(2.0f, acc[r][1])), ck1);
            float d2 = __fadd_rn(__fsub_rn(sa[r], __fmul_rn(2.0f, acc[r][2])), ck2);
            float d3 = __fadd_rn(__fsub_rn(sa[r], __fmul_rn(2.0f, acc[r][3])), ck3);
            unsigned long long p0 = ((unsigned long long)__float_as_uint(d0) << 32) | (unsigned)(c0);
            unsigned long long p1 = ((unsigned long long)__float_as_uint(d1) << 32) | (unsigned)(c0 + 256);
            unsigned long long p2 = ((unsigned long long)__float_as_uint(d2) << 32) | (unsigned)(c0 + 512);
            unsigned long long p3 = ((unsigned long long)__float_as_uint(d3) << 32) | (unsigned)(c0 + 768);
            unsigned long long pa = p0 < p1 ? p0 : p1;
            unsigned long long pb = p2 < p3 ? p2 : p3;
            unsigned long long pm = pa < pb ? pa : pb;
            for (int msk = 32; msk >= 1; msk >>= 1) {
                unsigned long long qv = __shfl_xor(pm, msk);
                pm = qv < pm ? qv : pm;
            }
            if ((tid & 63) == 0) atomicMin(&rescored[srow[r]], pm);
        }
    }
}

// ---------------- writeback z_q_st + loss partials + fused index fixup ----------------
__global__ __launch_bounds__(256) void writeback_kernel(
        const float* __restrict__ z, const float* __restrict__ emb,
        const unsigned long long* __restrict__ rescored,
        float* __restrict__ out_idx, float* __restrict__ out0,
        double* __restrict__ partials) {
    const int tid = threadIdx.x;
    const int base = blockIdx.x * 32;
    double acc = 0.0;
    for (int g = 0; g < 8; ++g) {
        int row = base + g * 4 + (tid >> 6);
        int d4 = tid & 63;
        unsigned long long rv = rescored[row];
        int idx;
        if (rv != ~0ull) {                   // flagged: exact rescore wins
            idx = (int)(unsigned)(rv & 0xffffffffull);
            if (d4 == 0) out_idx[row] = (float)idx;
        } else {
            idx = (int)out_idx[row];
        }
        float4 q4 = *(const float4*)&emb[(size_t)idx * D_DIM + d4 * 4];
        float4 z4 = *(const float4*)&z[(size_t)row * D_DIM + d4 * 4];
        float4 o;
        float dx;
        dx = q4.x - z4.x; o.x = z4.x + dx; acc += (double)dx * dx;
        dx = q4.y - z4.y; o.y = z4.y + dx; acc += (double)dx * dx;
        dx = q4.z - z4.z; o.z = z4.z + dx; acc += (double)dx * dx;
        dx = q4.w - z4.w; o.w = z4.w + dx; acc += (double)dx * dx;
        *(float4*)&out0[(size_t)row * D_DIM + d4 * 4] = o;
    }
    for (int m = 32; m >= 1; m >>= 1) acc += __shfl_xor(acc, m);
    __shared__ double sd[4];
    if ((tid & 63) == 0) sd[tid >> 6] = acc;
    __syncthreads();
    if (tid == 0) partials[blockIdx.x] = (sd[0] + sd[1]) + (sd[2] + sd[3]);
}

__global__ void finalize_kernel(const double* __restrict__ partials, float* __restrict__ out_loss) {
    __shared__ double sd[256];
    const int tid = threadIdx.x;
    double a = 0.0;
    for (int i = tid; i < 2048; i += 256) a += partials[i];
    sd[tid] = a;
    __syncthreads();
    for (int s = 128; s > 0; s >>= 1) {
        if (tid < s) sd[tid] += sd[tid + s];
        __syncthreads();
    }
    if (tid == 0) {
        double m = sd[0] / 16777216.0;
        out_loss[0] = (float)(m + 0.25 * m);
    }
}

extern "C" void kernel_launch(void* const* d_in, const int* in_sizes, int n_in,
                              void* d_out, int out_size, void* d_ws, size_t ws_size,
                              hipStream_t stream) {
    const float* z = (const float*)d_in[0];
    const float* emb = (const float*)d_in[1];
    float* out0 = (float*)d_out;
    float* out_loss = out0 + (size_t)N_ROWS * D_DIM;
    float* out_idx = out_loss + 1;

    char* ws = (char*)d_ws;
    float* rownorm = (float*)ws;
    float* cvec = (float*)(ws + 262144);
    unsigned short* emb_perm = (unsigned short*)(ws + 278528);
    int* flagcnt = (int*)(ws + 2375680);
    int* flaglist = (int*)(ws + 2375936);
    unsigned long long* rescored = (unsigned long long*)(ws + 2638080);
    double* partials = (double*)(ws + 3162368);

    // 32 MB z_perm scratch inside d_out (fully overwritten by writeback_kernel)
    unsigned short* z_perm = (unsigned short*)d_out;

    hipMemsetAsync(flagcnt, 0, sizeof(int), stream);
    hipMemsetAsync(rescored, 0xFF, (size_t)N_ROWS * 8, stream);

    norm_kernel<<<N_ROWS / 64, 256, 0, stream>>>(z, rownorm);
    norm_kernel<<<K_CODES / 64, 256, 0, stream>>>(emb, cvec);
    cvt_emb_kernel<<<512, 256, 0, stream>>>(emb, emb_perm);
    cvt_z_kernel<<<8192, 256, 0, stream>>>(z, z_perm);
    phaseB_kernel<<<N_ROWS / 64, 512, 0, stream>>>(z_perm, emb_perm, cvec, out_idx, flagcnt, flaglist);
    rescore_kernel<<<1024, 256, 0, stream>>>(z, emb, rownorm, cvec, flagcnt, flaglist, rescored);
    writeback_kernel<<<N_ROWS / 32, 256, 0, stream>>>(z, emb, rescored, out_idx, out0, partials);
    finalize_kernel<<<1, 256, 0, stream>>>(partials, out_loss);
}